// Round 1
// baseline (907.220 us; speedup 1.0000x reference)
//
#include <hip/hip_runtime.h>
#include <math.h>

#define HGT 150
#define WID 200
#define NPIX (HGT * WID)
#define KMAX 1024
#define PMAX 5

// ---------------------------------------------------------------------------
// Kernel 1: per (b,p) exact order-statistic selection via 3-level radix
// histogram on the float bit pattern (valid depths > 3.0 > 0, so the u32 bit
// pattern is monotone in value). Produces lb/ub outlier bounds per (b,p).
// ---------------------------------------------------------------------------
__global__ __launch_bounds__(256) void bounds_kernel(const float* __restrict__ in,
                                                     float* __restrict__ bounds) {
    const int bp = blockIdx.x;
    const int b = bp / PMAX;
    const int p = bp % PMAX;
    const float pid = (float)(p + 1);
    const float* __restrict__ depth = in + (size_t)b * 3 * NPIX;
    const float* __restrict__ ind   = depth + NPIX;
    const int tid = threadIdx.x;

    __shared__ uint32_t h[4 * 2048];     // reused across the 3 passes
    __shared__ int      s_n;
    __shared__ int      s_rank[4];       // target ranks (lo1, hi1, lo3, hi3), ascending
    __shared__ uint32_t s_pfx[4];        // resolved key prefix per rank
    __shared__ int      s_res[4];        // residual rank within prefix subset
    __shared__ uint32_t s_uniq[4];       // deduped prefixes
    __shared__ int      s_slot[4];       // rank -> uniq slot
    __shared__ int      s_nuniq;
    __shared__ int      s_done;

    // ---- pass 1: histogram of key[31:21] ----
    for (int j = tid; j < 2048; j += 256) h[j] = 0;
    __syncthreads();
    for (int i = tid; i < NPIX; i += 256) {
        float d = depth[i];
        if (rintf(ind[i]) == pid && d > 3.0f)
            atomicAdd(&h[__float_as_uint(d) >> 21], 1u);
    }
    __syncthreads();
    if (tid == 0) {
        int n = 0;
        for (int j = 0; j < 2048; ++j) n += (int)h[j];
        s_n = n;
        if (n == 0) {
            // no valid points: keep-mask is empty regardless of bounds
            bounds[2 * bp]     = __int_as_float(0x7F800000);   // +inf
            bounds[2 * bp + 1] = __int_as_float(0xFF800000);   // -inf
            s_done = 1;
        } else {
            s_done = 0;
            float nf   = (float)n;
            float pos1 = 0.25f * fmaxf(nf - 1.0f, 0.0f);   // exact in f32 (n-1 < 2^24)
            float pos3 = 0.75f * fmaxf(nf - 1.0f, 0.0f);
            s_rank[0] = (int)floorf(pos1);
            s_rank[1] = (int)ceilf(pos1);
            s_rank[2] = (int)floorf(pos3);
            s_rank[3] = (int)ceilf(pos3);
            uint32_t c = 0;
            for (int j = 0; j < 2048 && c <= (uint32_t)s_rank[3]; ++j) {
                uint32_t c2 = c + h[j];
#pragma unroll
                for (int k = 0; k < 4; ++k)
                    if ((uint32_t)s_rank[k] >= c && (uint32_t)s_rank[k] < c2) {
                        s_pfx[k] = (uint32_t)j;
                        s_res[k] = s_rank[k] - (int)c;
                    }
                c = c2;
            }
            int nu = 0;
#pragma unroll
            for (int k = 0; k < 4; ++k) {
                int found = -1;
                for (int u = 0; u < nu; ++u)
                    if (s_uniq[u] == s_pfx[k]) found = u;
                if (found < 0) { s_uniq[nu] = s_pfx[k]; found = nu; ++nu; }
                s_slot[k] = found;
            }
            s_nuniq = nu;
        }
    }
    __syncthreads();
    if (s_done) return;

    // ---- pass 2: histogram of key[20:10] within matched top bins ----
    int nu = s_nuniq;
    for (int j = tid; j < nu * 2048; j += 256) h[j] = 0;
    __syncthreads();
    for (int i = tid; i < NPIX; i += 256) {
        float d = depth[i];
        if (rintf(ind[i]) == pid && d > 3.0f) {
            uint32_t key = __float_as_uint(d);
            uint32_t top = key >> 21;
            for (int u = 0; u < nu; ++u)
                if (top == s_uniq[u])
                    atomicAdd(&h[u * 2048 + ((key >> 10) & 0x7FFu)], 1u);
        }
    }
    __syncthreads();
    if (tid == 0) {
        uint32_t newpfx[4]; int newres[4];
        for (int k = 0; k < 4; ++k) {
            uint32_t* hh = &h[s_slot[k] * 2048];
            uint32_t c = 0;
            int r = s_res[k];
            for (int j = 0; j < 2048; ++j) {
                uint32_t c2 = c + hh[j];
                if ((uint32_t)r < c2) {
                    newpfx[k] = (s_pfx[k] << 11) | (uint32_t)j;
                    newres[k] = r - (int)c;
                    break;
                }
                c = c2;
            }
        }
        int nu2 = 0;
        uint32_t uq[4];
        for (int k = 0; k < 4; ++k) {
            int found = -1;
            for (int u = 0; u < nu2; ++u)
                if (uq[u] == newpfx[k]) found = u;
            if (found < 0) { uq[nu2] = newpfx[k]; found = nu2; ++nu2; }
            s_slot[k] = found;
            s_pfx[k]  = newpfx[k];
            s_res[k]  = newres[k];
        }
        for (int u = 0; u < nu2; ++u) s_uniq[u] = uq[u];
        s_nuniq = nu2;
    }
    __syncthreads();

    // ---- pass 3: histogram of key[9:0] within matched 22-bit prefixes ----
    nu = s_nuniq;
    for (int j = tid; j < nu * 1024; j += 256) h[j] = 0;
    __syncthreads();
    for (int i = tid; i < NPIX; i += 256) {
        float d = depth[i];
        if (rintf(ind[i]) == pid && d > 3.0f) {
            uint32_t key = __float_as_uint(d);
            uint32_t top22 = key >> 10;
            for (int u = 0; u < nu; ++u)
                if (top22 == s_uniq[u])
                    atomicAdd(&h[u * 1024 + (key & 0x3FFu)], 1u);
        }
    }
    __syncthreads();
    if (tid == 0) {
        float v[4];
        for (int k = 0; k < 4; ++k) {
            uint32_t* hh = &h[s_slot[k] * 1024];
            uint32_t c = 0, val = 0;
            int r = s_res[k];
            for (int j = 0; j < 1024; ++j) {
                uint32_t c2 = c + hh[j];
                if ((uint32_t)r < c2) { val = (s_pfx[k] << 10) | (uint32_t)j; break; }
                c = c2;
            }
            v[k] = __uint_as_float(val);
        }
        float nf   = (float)s_n;
        float pos1 = 0.25f * fmaxf(nf - 1.0f, 0.0f);
        float pos3 = 0.75f * fmaxf(nf - 1.0f, 0.0f);
        float f1 = pos1 - floorf(pos1);
        float f3 = pos3 - floorf(pos3);
        float q1 = v[0] + (v[1] - v[0]) * f1;
        float q3 = v[2] + (v[3] - v[2]) * f3;
        float iqr = q3 - q1;
        bounds[2 * bp]     = q1 - 1.5f * iqr;
        bounds[2 * bp + 1] = q3 + 1.5f * iqr;
    }
}

// ---------------------------------------------------------------------------
// Kernel 2: per (b,p) ordered stream compaction of kept pixels into the
// first K slots; zero-fill the rest; presence flag in slot K channel 0.
// ---------------------------------------------------------------------------
__global__ __launch_bounds__(256) void compact_kernel(const float* __restrict__ in,
                                                      const float* __restrict__ bounds,
                                                      float* __restrict__ out) {
    const int bp = blockIdx.x;
    const int b = bp / PMAX;
    const int p = bp % PMAX;
    const float pid = (float)(p + 1);
    const float* __restrict__ depth = in + (size_t)b * 3 * NPIX;
    const float* __restrict__ ind   = depth + NPIX;
    const int tid  = threadIdx.x;
    const int lane = tid & 63;
    const int wv   = tid >> 6;

    const float lb = bounds[2 * bp];
    const float ub = bounds[2 * bp + 1];

    // camera intrinsics, double precision to match numpy's float64 fx/fy
    const double fx = (double)WID / (2.0 * tan((81.0 * M_PI / 180.0) / 2.0));
    const double fy = (double)HGT / (2.0 * tan((59.0 * M_PI / 180.0) / 2.0));

    __shared__ uint32_t wtot[4];
    __shared__ uint32_t s_base;
    if (tid == 0) s_base = 0;
    __syncthreads();

    const int stride_c = PMAX * (KMAX + 1);
    float* outB = out + (size_t)b * 3 * stride_c + (size_t)p * (KMAX + 1);

    for (int chunk = 0; chunk < NPIX; chunk += 256) {
        int i = chunk + tid;
        bool keep = false;
        float d = 0.0f;
        if (i < NPIX) {
            d = depth[i];
            keep = (rintf(ind[i]) == pid) && (d > 3.0f) && (d >= lb) && (d <= ub);
        }
        unsigned long long m = __ballot(keep);
        uint32_t wpref = (uint32_t)__popcll(m & ((1ULL << lane) - 1ULL));
        if (lane == 0) wtot[wv] = (uint32_t)__popcll(m);
        __syncthreads();
        uint32_t base = s_base;
        for (int w = 0; w < wv; ++w) base += wtot[w];
        uint32_t r = base + wpref;
        if (keep && r < KMAX) {
            int row = i / WID;
            int col = i - row * WID;
            float xc = (float)(((double)col - (double)WID / 2.0) / fx);
            float yc = (float)(((double)row - (double)HGT / 2.0) / fy);
            outB[r]                = xc * d;
            outB[stride_c + r]     = yc * d;
            outB[2 * stride_c + r] = d;
        }
        __syncthreads();
        if (tid == 0) s_base += wtot[0] + wtot[1] + wtot[2] + wtot[3];
        __syncthreads();
    }

    uint32_t count = s_base;
    uint32_t start = count < KMAX ? count : KMAX;
    for (uint32_t r = start + tid; r < KMAX; r += 256) {
        outB[r]                = 0.0f;
        outB[stride_c + r]     = 0.0f;
        outB[2 * stride_c + r] = 0.0f;
    }
    if (tid == 0) {
        outB[KMAX]                = (count > 0) ? 1.0f : 0.0f;
        outB[stride_c + KMAX]     = 0.0f;
        outB[2 * stride_c + KMAX] = 0.0f;
    }
}

extern "C" void kernel_launch(void* const* d_in, const int* in_sizes, int n_in,
                              void* d_out, int out_size, void* d_ws, size_t ws_size,
                              hipStream_t stream) {
    (void)n_in; (void)out_size; (void)ws_size;
    const float* in = (const float*)d_in[0];
    float* out = (float*)d_out;
    float* bounds = (float*)d_ws;   // 2 floats per (b,p): lb, ub

    const int B = in_sizes[0] / (3 * NPIX);
    const int nblocks = B * PMAX;

    bounds_kernel<<<nblocks, 256, 0, stream>>>(in, bounds);
    compact_kernel<<<nblocks, 256, 0, stream>>>(in, bounds, out);
}

// Round 2
// 177.476 us; speedup vs baseline: 5.1118x; 5.1118x over previous
//
#include <hip/hip_runtime.h>
#include <math.h>

#define HGT 150
#define WID 200
#define NPIX 30000
#define NF4  7500          // NPIX/4 (exact)
#define F4_PER_ROW 50      // WID/4
#define KMAX 1024
#define PMAX 5
#define NW32 938           // ceil(NPIX/32) nibble-mask words
#define STRIDE_C (PMAX*(KMAX+1))

__device__ __forceinline__ uint32_t wave_incl_scan(uint32_t x, int lane) {
#pragma unroll
    for (int off = 1; off < 64; off <<= 1) {
        uint32_t y = __shfl_up(x, (unsigned)off, 64);
        if (lane >= off) x += y;
    }
    return x;
}

// Parallel rank-location in a histogram of 256*seg bins.
// For each rank k (0..3) with (!with_slot || s_slot[k]==g), finds the bin
// containing residual rank (s_rank[k]-s_base[k]) and the count below that bin.
// Results in s_tbin[k]/s_tbel[k]. Ends with a barrier.
__device__ void locate_ranks(const uint32_t* hh, int seg,
                             const uint32_t* s_rank, const uint32_t* s_base,
                             const int* s_slot, int g, int with_slot,
                             uint32_t* s_tbin, uint32_t* s_tbel, uint32_t* s_ws) {
    const int tid = threadIdx.x, lane = tid & 63, wv = tid >> 6;
    const uint32_t* mine = hh + tid * seg;
    uint32_t segsum = 0;
    for (int j = 0; j < seg; ++j) segsum += mine[j];
    uint32_t inc = wave_incl_scan(segsum, lane);
    if (lane == 63) s_ws[wv] = inc;
    __syncthreads();
    uint32_t tbase = inc - segsum;
    for (int w = 0; w < wv; ++w) tbase += s_ws[w];
#pragma unroll
    for (int k = 0; k < 4; ++k) {
        if (with_slot && s_slot[k] != g) continue;
        uint32_t r = s_rank[k] - s_base[k];
        if (r >= tbase && r < tbase + segsum) {
            uint32_t c = tbase;
            for (int j = 0; j < seg; ++j) {
                uint32_t h = mine[j];
                if (r < c + h) { s_tbin[k] = (uint32_t)(tid * seg + j); s_tbel[k] = c; break; }
                c += h;
            }
        }
    }
    __syncthreads();
}

__global__ __launch_bounds__(256, 4) void fused(const float* __restrict__ in,
                                                float* __restrict__ out, int B) {
    // XCD-aware remap: blocks with same (blockIdx&7) share an XCD; give each
    // XCD a contiguous batch range so its 4MB L2 holds the working set.
    const int nbp = B * PMAX;
    int x = blockIdx.x, b, p;
    if ((nbp & 7) == 0) {
        int per = nbp >> 3;
        int slot = (x & 7) * per + (x >> 3);
        b = slot / PMAX; p = slot - b * PMAX;
    } else { b = x / PMAX; p = x - b * PMAX; }

    const float pid = (float)(p + 1);
    const float* __restrict__ depth = in + (size_t)b * 3 * NPIX;
    const float4* __restrict__ depth4 = (const float4*)depth;
    const float4* __restrict__ ind4   = (const float4*)(depth + NPIX);
    const int tid = threadIdx.x, lane = tid & 63, wv = tid >> 6;

    __shared__ uint32_t hist[2][4096];   // 32 KB, reused across levels
    __shared__ uint32_t vb[NW32];        // validity nibbles, 4 px/word*8
    __shared__ float xc_tab[WID];
    __shared__ float yc_tab[HGT];
    __shared__ uint32_t s_ws[4];
    __shared__ uint32_t s_rank[4], s_base[4], s_tbin[4], s_tbel[4], s_pfx[4];
    __shared__ uint32_t s_u[4];
    __shared__ int s_slot[4], s_nu;
    __shared__ uint32_t s_n;
    __shared__ float s_lbub[2];

    // ---- init LDS + ray tables ----
    for (int i = tid; i < 2 * 4096; i += 256) ((uint32_t*)hist)[i] = 0;
    for (int i = tid; i < NW32; i += 256) vb[i] = 0;
    {
        const double fxd = (double)WID / (2.0 * tan((81.0 * M_PI / 180.0) * 0.5));
        const double fyd = (double)HGT / (2.0 * tan((59.0 * M_PI / 180.0) * 0.5));
        for (int i = tid; i < WID; i += 256) xc_tab[i] = (float)(((double)i - (double)WID / 2.0) / fxd);
        for (int i = tid; i < HGT; i += 256) yc_tab[i] = (float)(((double)i - (double)HGT / 2.0) / fyd);
    }
    __syncthreads();

    // ---- pass 1: validity nibbles + level-1 histogram (key>>20) ----
    for (int f = tid; f < NF4; f += 256) {
        float4 d4 = depth4[f];
        float4 i4 = ind4[f];
        const float* dd = (const float*)&d4;
        const float* ii = (const float*)&i4;
        uint32_t nib = 0;
#pragma unroll
        for (int j = 0; j < 4; ++j) {
            if (rintf(ii[j]) == pid && dd[j] > 3.0f) {
                nib |= 1u << j;
                atomicAdd(&hist[0][__float_as_uint(dd[j]) >> 20], 1u);
            }
        }
        if (nib) atomicOr(&vb[f >> 3], nib << ((f & 7) * 4));
    }
    __syncthreads();

    // ---- n + ranks ----
    {
        const uint32_t* mine = &hist[0][tid * 16];
        uint32_t segsum = 0;
        for (int j = 0; j < 16; ++j) segsum += mine[j];
        uint32_t incw = wave_incl_scan(segsum, lane);
        if (lane == 63) s_ws[wv] = incw;
        __syncthreads();
        uint32_t total = s_ws[0] + s_ws[1] + s_ws[2] + s_ws[3];
        if (tid == 0) {
            s_n = total;
            if (total > 0) {
                float nf = (float)total;
                float pos1 = 0.25f * fmaxf(nf - 1.0f, 0.0f);
                float pos3 = 0.75f * fmaxf(nf - 1.0f, 0.0f);
                s_rank[0] = (uint32_t)floorf(pos1);
                s_rank[1] = (uint32_t)ceilf(pos1);
                s_rank[2] = (uint32_t)floorf(pos3);
                s_rank[3] = (uint32_t)ceilf(pos3);
                for (int k = 0; k < 4; ++k) s_base[k] = 0;
            }
        }
        __syncthreads();
    }

    float* outB = out + (size_t)b * 3 * STRIDE_C + p * (KMAX + 1);
    if (s_n == 0) {   // uniform branch: empty segment, all zeros incl. flag
        for (int r = tid; r <= KMAX; r += 256) {
            outB[r] = 0.f; outB[STRIDE_C + r] = 0.f; outB[2 * STRIDE_C + r] = 0.f;
        }
        return;
    }

    // ---- locate level-1 bins ----
    locate_ranks(hist[0], 16, s_rank, s_base, s_slot, 0, 0, s_tbin, s_tbel, s_ws);
    if (tid == 0) {
        int nu = 0;
        for (int k = 0; k < 4; ++k) { s_pfx[k] = s_tbin[k]; s_base[k] = s_tbel[k]; }
        for (int k = 0; k < 4; ++k) {
            int fnd = -1;
            for (int u = 0; u < nu; ++u) if (s_u[u] == s_pfx[k]) fnd = u;
            if (fnd < 0) { s_u[nu] = s_pfx[k]; fnd = nu; ++nu; }
            s_slot[k] = fnd;
        }
        s_nu = nu;
    }
    __syncthreads();

    // ---- level 2: (key>>8)&0xFFF within matched level-1 bins ----
    int nu = s_nu;
    for (int b0 = 0; b0 < nu; b0 += 2) {
        int nb = nu - b0; if (nb > 2) nb = 2;
        for (int i = tid; i < nb * 4096; i += 256) ((uint32_t*)hist)[i] = 0;
        __syncthreads();
        uint32_t u0 = s_u[b0];
        uint32_t u1 = (nb > 1) ? s_u[b0 + 1] : 0xFFFFFFFFu;
        for (int f = tid; f < NF4; f += 256) {
            uint32_t nib = (vb[f >> 3] >> ((f & 7) * 4)) & 0xFu;
            if (!nib) continue;
            float4 d4 = depth4[f];
            const float* dd = (const float*)&d4;
#pragma unroll
            for (int j = 0; j < 4; ++j) if ((nib >> j) & 1) {
                uint32_t key = __float_as_uint(dd[j]);
                uint32_t top = key >> 20;
                if (top == u0)      atomicAdd(&hist[0][(key >> 8) & 0xFFFu], 1u);
                else if (top == u1) atomicAdd(&hist[1][(key >> 8) & 0xFFFu], 1u);
            }
        }
        __syncthreads();
        for (int g = 0; g < nb; ++g) {
            locate_ranks(hist[g], 16, s_rank, s_base, s_slot, b0 + g, 1, s_tbin, s_tbel, s_ws);
            if (tid == 0) {
                for (int k = 0; k < 4; ++k) if (s_slot[k] == b0 + g) {
                    s_pfx[k] = (s_pfx[k] << 12) | s_tbin[k];
                    s_base[k] += s_tbel[k];
                }
            }
            __syncthreads();
        }
    }
    if (tid == 0) {   // dedup 24-bit prefixes
        int nu2 = 0;
        for (int k = 0; k < 4; ++k) {
            int fnd = -1;
            for (int u = 0; u < nu2; ++u) if (s_u[u] == s_pfx[k]) fnd = u;
            if (fnd < 0) { s_u[nu2] = s_pfx[k]; fnd = nu2; ++nu2; }
            s_slot[k] = fnd;
        }
        s_nu = nu2;
    }
    __syncthreads();

    // ---- level 3: key&0xFF within matched 24-bit prefixes (<=4 x 256 bins) ----
    int nu3 = s_nu;
    uint32_t* h3 = (uint32_t*)hist;
    for (int i = tid; i < 4 * 256; i += 256) h3[i] = 0;
    __syncthreads();
    uint32_t ru[4];
#pragma unroll
    for (int u = 0; u < 4; ++u) ru[u] = (u < nu3) ? s_u[u] : 0xFFFFFFFFu;
    for (int f = tid; f < NF4; f += 256) {
        uint32_t nib = (vb[f >> 3] >> ((f & 7) * 4)) & 0xFu;
        if (!nib) continue;
        float4 d4 = depth4[f];
        const float* dd = (const float*)&d4;
#pragma unroll
        for (int j = 0; j < 4; ++j) if ((nib >> j) & 1) {
            uint32_t key = __float_as_uint(dd[j]);
            uint32_t pfx = key >> 8;
            if (pfx == ru[0])      atomicAdd(&h3[0 * 256 + (key & 0xFFu)], 1u);
            else if (pfx == ru[1]) atomicAdd(&h3[1 * 256 + (key & 0xFFu)], 1u);
            else if (pfx == ru[2]) atomicAdd(&h3[2 * 256 + (key & 0xFFu)], 1u);
            else if (pfx == ru[3]) atomicAdd(&h3[3 * 256 + (key & 0xFFu)], 1u);
        }
    }
    __syncthreads();
    for (int g = 0; g < nu3; ++g)
        locate_ranks(h3 + g * 256, 1, s_rank, s_base, s_slot, g, 1, s_tbin, s_tbel, s_ws);
    if (tid == 0) {
        float v[4];
        for (int k = 0; k < 4; ++k) v[k] = __uint_as_float((s_pfx[k] << 8) | s_tbin[k]);
        float nf = (float)s_n;
        float pos1 = 0.25f * fmaxf(nf - 1.0f, 0.0f);
        float pos3 = 0.75f * fmaxf(nf - 1.0f, 0.0f);
        float f1 = pos1 - floorf(pos1);
        float f3 = pos3 - floorf(pos3);
        float q1 = v[0] + (v[1] - v[0]) * f1;
        float q3 = v[2] + (v[3] - v[2]) * f3;
        float iqr = q3 - q1;
        s_lbub[0] = q1 - 1.5f * iqr;
        s_lbub[1] = q3 + 1.5f * iqr;
    }
    __syncthreads();

    // ---- compact: first K kept points in raster order ----
    const float lb = s_lbub[0], ub = s_lbub[1];
    uint32_t run_base = 0;
    for (int c0 = 0; c0 < NF4; c0 += 256) {
        int f = c0 + tid;
        uint32_t nib = 0;
        float4 d4;
        if (f < NF4) {
            nib = (vb[f >> 3] >> ((f & 7) * 4)) & 0xFu;
            if (nib) {
                d4 = depth4[f];
                const float* dd = (const float*)&d4;
                uint32_t nib2 = 0;
#pragma unroll
                for (int j = 0; j < 4; ++j)
                    if (((nib >> j) & 1) && dd[j] >= lb && dd[j] <= ub) nib2 |= 1u << j;
                nib = nib2;
            }
        }
        uint32_t cnt = (uint32_t)__popc(nib);
        uint32_t inc = wave_incl_scan(cnt, lane);
        if (lane == 63) s_ws[wv] = inc;
        __syncthreads();
        uint32_t base = run_base + inc - cnt;
        for (int w = 0; w < wv; ++w) base += s_ws[w];
        uint32_t tot = s_ws[0] + s_ws[1] + s_ws[2] + s_ws[3];
        if (nib && base < KMAX) {
            const float* dd = (const float*)&d4;
            int row = f / F4_PER_ROW;
            int col0 = (f - row * F4_PER_ROW) * 4;
            float yc = yc_tab[row];
            uint32_t r = base;
#pragma unroll
            for (int j = 0; j < 4; ++j) if ((nib >> j) & 1) {
                if (r < KMAX) {
                    float d = dd[j];
                    outB[r] = xc_tab[col0 + j] * d;
                    outB[STRIDE_C + r] = yc * d;
                    outB[2 * STRIDE_C + r] = d;
                }
                ++r;
            }
        }
        run_base += tot;
        __syncthreads();   // protect s_ws for next chunk
    }
    uint32_t count = run_base;
    uint32_t start = count < KMAX ? count : KMAX;
    for (uint32_t r = start + tid; r < KMAX; r += 256) {
        outB[r] = 0.f; outB[STRIDE_C + r] = 0.f; outB[2 * STRIDE_C + r] = 0.f;
    }
    if (tid == 0) {
        outB[KMAX] = (count > 0) ? 1.0f : 0.0f;
        outB[STRIDE_C + KMAX] = 0.f;
        outB[2 * STRIDE_C + KMAX] = 0.f;
    }
}

extern "C" void kernel_launch(void* const* d_in, const int* in_sizes, int n_in,
                              void* d_out, int out_size, void* d_ws, size_t ws_size,
                              hipStream_t stream) {
    (void)n_in; (void)out_size; (void)d_ws; (void)ws_size;
    const float* in = (const float*)d_in[0];
    float* out = (float*)d_out;
    const int B = in_sizes[0] / (3 * NPIX);
    fused<<<B * PMAX, 256, 0, stream>>>(in, out, B);
}

// Round 3
// 152.081 us; speedup vs baseline: 5.9654x; 1.1670x over previous
//
#include <hip/hip_runtime.h>
#include <math.h>

#define HGT 150
#define WID 200
#define NPIX 30000
#define NF4  7500          // NPIX/4
#define KMAX 1024
#define PMAX 5
#define CAP  6144          // LDS list capacity; n_valid ~3125+-53 => 57 sigma margin
#define STRIDE_C (PMAX*(KMAX+1))
#define SEG_F4 30          // ceil(NF4/256) float4-groups per thread (contiguous)

__device__ __forceinline__ uint32_t wave_incl_scan(uint32_t x, int lane) {
#pragma unroll
    for (int off = 1; off < 64; off <<= 1) {
        uint32_t y = __shfl_up(x, (unsigned)off, 64);
        if (lane >= off) x += y;
    }
    return x;
}

// Parallel rank-location in a histogram of 256*seg bins (validated in R2).
__device__ void locate_ranks(const uint32_t* hh, int seg,
                             const uint32_t* s_rank, const uint32_t* s_base,
                             const int* s_slot, int g, int with_slot,
                             uint32_t* s_tbin, uint32_t* s_tbel, uint32_t* s_ws) {
    const int tid = threadIdx.x, lane = tid & 63, wv = tid >> 6;
    const uint32_t* mine = hh + tid * seg;
    uint32_t segsum = 0;
    for (int j = 0; j < seg; ++j) segsum += mine[j];
    uint32_t inc = wave_incl_scan(segsum, lane);
    if (lane == 63) s_ws[wv] = inc;
    __syncthreads();
    uint32_t tbase = inc - segsum;
    for (int w = 0; w < wv; ++w) tbase += s_ws[w];
#pragma unroll
    for (int k = 0; k < 4; ++k) {
        if (with_slot && s_slot[k] != g) continue;
        uint32_t r = s_rank[k] - s_base[k];
        if (r >= tbase && r < tbase + segsum) {
            uint32_t c = tbase;
            for (int j = 0; j < seg; ++j) {
                uint32_t h = mine[j];
                if (r < c + h) { s_tbin[k] = (uint32_t)(tid * seg + j); s_tbel[k] = c; break; }
                c += h;
            }
        }
    }
    __syncthreads();
}

__global__ __launch_bounds__(256, 4) void fused(const float* __restrict__ in,
                                                float* __restrict__ out, int B) {
    // XCD-aware remap: same (blockIdx&7) -> same XCD; contiguous batch range per XCD.
    const int nbp = B * PMAX;
    int x = blockIdx.x, b, p;
    if ((nbp & 7) == 0) {
        int per = nbp >> 3;
        int slot = (x & 7) * per + (x >> 3);
        b = slot / PMAX; p = slot - b * PMAX;
    } else { b = x / PMAX; p = x - b * PMAX; }

    const float pid = (float)(p + 1);
    const float4* __restrict__ depth4 = (const float4*)(in + (size_t)b * 3 * NPIX);
    const float4* __restrict__ ind4   = depth4 + NF4;
    const int tid = threadIdx.x, lane = tid & 63, wv = tid >> 6;

    __shared__ uint32_t keys[CAP];         // 24 KB: valid depth keys, raster order
    __shared__ unsigned short sidx[CAP];   // 12 KB: pixel index per key
    __shared__ uint32_t hist[2048];        //  8 KB: radix histogram (reused)
    __shared__ float xc_tab[WID];
    __shared__ float yc_tab[HGT];
    __shared__ uint32_t s_ws[4];
    __shared__ uint32_t s_rank[4], s_base[4], s_tbin[4], s_tbel[4], s_pfx[4], s_u[4];
    __shared__ int s_slot[4], s_nu;
    __shared__ uint32_t s_cnt;
    __shared__ float s_lbub[2];

    // ray tables (double precision to match numpy fx/fy)
    {
        const double fxd = (double)WID / (2.0 * tan((81.0 * M_PI / 180.0) * 0.5));
        const double fyd = (double)HGT / (2.0 * tan((59.0 * M_PI / 180.0) * 0.5));
        for (int i = tid; i < WID; i += 256) xc_tab[i] = (float)(((double)i - (double)WID / 2.0) / fxd);
        for (int i = tid; i < HGT; i += 256) yc_tab[i] = (float)(((double)i - (double)HGT / 2.0) / fyd);
    }

    // ---- Phase A: per-thread contiguous segment -> validity nibbles + count ----
    uint32_t m[4] = {0u, 0u, 0u, 0u};
    uint32_t cnt = 0;
    const int f0 = tid * SEG_F4;
#pragma unroll
    for (int w = 0; w < 4; ++w) {
#pragma unroll
        for (int j2 = 0; j2 < 8; ++j2) {
            const int j = w * 8 + j2;
            if (j < SEG_F4) {
                int f = f0 + j;
                if (f < NF4) {
                    float4 d4 = depth4[f];
                    float4 i4 = ind4[f];
                    const float* dd = (const float*)&d4;
                    const float* ii = (const float*)&i4;
                    uint32_t nib = 0;
#pragma unroll
                    for (int k = 0; k < 4; ++k)
                        if (rintf(ii[k]) == pid && dd[k] > 3.0f) nib |= 1u << k;
                    cnt += (uint32_t)__popc(nib);
                    m[w] |= nib << (4 * j2);
                }
            }
        }
    }
    // block scan -> base offset per thread, total n
    uint32_t inc = wave_incl_scan(cnt, lane);
    if (lane == 63) s_ws[wv] = inc;
    __syncthreads();
    uint32_t base = inc - cnt;
    for (int w = 0; w < wv; ++w) base += s_ws[w];
    const uint32_t n = s_ws[0] + s_ws[1] + s_ws[2] + s_ws[3];

    float* outB = out + (size_t)b * 3 * STRIDE_C + p * (KMAX + 1);

    if (n == 0) {   // uniform: empty segment -> all zeros incl. flag
        for (int r = tid; r <= KMAX; r += 256) {
            outB[r] = 0.f; outB[STRIDE_C + r] = 0.f; outB[2 * STRIDE_C + r] = 0.f;
        }
        return;
    }

    if (n > CAP) {
        // ---- correctness-only fallback (never triggered by bench data) ----
        const float* depth = (const float*)depth4;
        const float* ind   = (const float*)ind4;
        if (tid == 0) {
            uint32_t rank[4], pfx[4], res[4];
            float nf = (float)n;
            float pos1 = 0.25f * fmaxf(nf - 1.0f, 0.0f);
            float pos3 = 0.75f * fmaxf(nf - 1.0f, 0.0f);
            rank[0] = (uint32_t)floorf(pos1); rank[1] = (uint32_t)ceilf(pos1);
            rank[2] = (uint32_t)floorf(pos3); rank[3] = (uint32_t)ceilf(pos3);
            // level 1: key>>21
            for (int j = 0; j < 2048; ++j) hist[j] = 0;
            for (int i = 0; i < NPIX; ++i) {
                float d = depth[i];
                if (rintf(ind[i]) == pid && d > 3.0f) hist[__float_as_uint(d) >> 21]++;
            }
            for (int k = 0; k < 4; ++k) {
                uint32_t c = 0;
                for (int j = 0; j < 2048; ++j) {
                    uint32_t c2 = c + hist[j];
                    if (rank[k] < c2) { pfx[k] = (uint32_t)j; res[k] = rank[k] - c; break; }
                    c = c2;
                }
            }
            // level 2: (key>>10)&0x7FF per rank
            for (int k = 0; k < 4; ++k) {
                for (int j = 0; j < 2048; ++j) hist[j] = 0;
                for (int i = 0; i < NPIX; ++i) {
                    float d = depth[i];
                    if (rintf(ind[i]) == pid && d > 3.0f) {
                        uint32_t key = __float_as_uint(d);
                        if ((key >> 21) == pfx[k]) hist[(key >> 10) & 0x7FFu]++;
                    }
                }
                uint32_t c = 0;
                for (int j = 0; j < 2048; ++j) {
                    uint32_t c2 = c + hist[j];
                    if (res[k] < c2) { pfx[k] = (pfx[k] << 11) | (uint32_t)j; res[k] -= c; break; }
                    c = c2;
                }
            }
            // level 3: key&0x3FF per rank
            float v[4];
            for (int k = 0; k < 4; ++k) {
                for (int j = 0; j < 1024; ++j) hist[j] = 0;
                for (int i = 0; i < NPIX; ++i) {
                    float d = depth[i];
                    if (rintf(ind[i]) == pid && d > 3.0f) {
                        uint32_t key = __float_as_uint(d);
                        if ((key >> 10) == pfx[k]) hist[key & 0x3FFu]++;
                    }
                }
                uint32_t c = 0; uint32_t val = 0;
                for (int j = 0; j < 1024; ++j) {
                    uint32_t c2 = c + hist[j];
                    if (res[k] < c2) { val = (pfx[k] << 10) | (uint32_t)j; break; }
                    c = c2;
                }
                v[k] = __uint_as_float(val);
            }
            float f1 = pos1 - floorf(pos1);
            float f3 = pos3 - floorf(pos3);
            float q1 = v[0] + (v[1] - v[0]) * f1;
            float q3 = v[2] + (v[3] - v[2]) * f3;
            float iqr = q3 - q1;
            s_lbub[0] = q1 - 1.5f * iqr;
            s_lbub[1] = q3 + 1.5f * iqr;
        }
        __syncthreads();
        if (tid == 0) {
            float lb = s_lbub[0], ub = s_lbub[1];
            uint32_t r = 0;
            for (int i = 0; i < NPIX; ++i) {
                float d = depth[i];
                if (rintf(ind[i]) == pid && d > 3.0f && d >= lb && d <= ub) {
                    if (r < KMAX) {
                        int row = i / WID, col = i - row * WID;
                        outB[r] = xc_tab[col] * d;
                        outB[STRIDE_C + r] = yc_tab[row] * d;
                        outB[2 * STRIDE_C + r] = d;
                    }
                    ++r;
                }
            }
            s_cnt = r;
        }
        __syncthreads();
        uint32_t count = s_cnt;
        uint32_t start = count < KMAX ? count : KMAX;
        for (uint32_t r = start + tid; r < KMAX; r += 256) {
            outB[r] = 0.f; outB[STRIDE_C + r] = 0.f; outB[2 * STRIDE_C + r] = 0.f;
        }
        if (tid == 0) {
            outB[KMAX] = (count > 0) ? 1.0f : 0.0f;
            outB[STRIDE_C + KMAX] = 0.f;
            outB[2 * STRIDE_C + KMAX] = 0.f;
        }
        return;
    }

    // ---- Phase B: replay -> compacted (key, idx) list in LDS; clear hist ----
    {
        uint32_t pos = base;
#pragma unroll
        for (int w = 0; w < 4; ++w) {
#pragma unroll
            for (int j2 = 0; j2 < 8; ++j2) {
                const int j = w * 8 + j2;
                if (j < SEG_F4) {
                    int f = f0 + j;
                    if (f < NF4) {
                        uint32_t nib = (m[w] >> (4 * j2)) & 0xFu;
                        if (nib) {
                            float4 d4 = depth4[f];
                            const float* dd = (const float*)&d4;
#pragma unroll
                            for (int k = 0; k < 4; ++k)
                                if ((nib >> k) & 1) {
                                    keys[pos] = __float_as_uint(dd[k]);
                                    sidx[pos] = (unsigned short)(f * 4 + k);
                                    ++pos;
                                }
                        }
                    }
                }
            }
        }
        for (int i = tid; i < 2048; i += 256) hist[i] = 0;
        if (tid == 0) {
            float nf = (float)n;
            float pos1 = 0.25f * fmaxf(nf - 1.0f, 0.0f);
            float pos3 = 0.75f * fmaxf(nf - 1.0f, 0.0f);
            s_rank[0] = (uint32_t)floorf(pos1);
            s_rank[1] = (uint32_t)ceilf(pos1);
            s_rank[2] = (uint32_t)floorf(pos3);
            s_rank[3] = (uint32_t)ceilf(pos3);
            for (int k = 0; k < 4; ++k) s_base[k] = 0;
        }
        __syncthreads();
    }

    // ---- level 1: key>>21 (2048 bins) over LDS list ----
    for (uint32_t i = tid; i < n; i += 256) atomicAdd(&hist[keys[i] >> 21], 1u);
    __syncthreads();
    locate_ranks(hist, 8, s_rank, s_base, s_slot, 0, 0, s_tbin, s_tbel, s_ws);
    if (tid == 0) {
        int nu = 0;
        for (int k = 0; k < 4; ++k) { s_pfx[k] = s_tbin[k]; s_base[k] = s_tbel[k]; }
        for (int k = 0; k < 4; ++k) {
            int fnd = -1;
            for (int u = 0; u < nu; ++u) if (s_u[u] == s_pfx[k]) fnd = u;
            if (fnd < 0) { s_u[nu] = s_pfx[k]; fnd = nu; ++nu; }
            s_slot[k] = fnd;
        }
        s_nu = nu;
    }
    __syncthreads();

    // ---- level 2: (key>>10)&0x7FF within matched level-1 bins ----
    {
        int nu = s_nu;
        for (int g = 0; g < nu; ++g) {
            for (int i = tid; i < 2048; i += 256) hist[i] = 0;
            __syncthreads();
            uint32_t u = s_u[g];
            for (uint32_t i = tid; i < n; i += 256) {
                uint32_t key = keys[i];
                if ((key >> 21) == u) atomicAdd(&hist[(key >> 10) & 0x7FFu], 1u);
            }
            __syncthreads();
            locate_ranks(hist, 8, s_rank, s_base, s_slot, g, 1, s_tbin, s_tbel, s_ws);
            if (tid == 0) {
                for (int k = 0; k < 4; ++k) if (s_slot[k] == g) {
                    s_pfx[k] = (s_pfx[k] << 11) | s_tbin[k];
                    s_base[k] += s_tbel[k];
                }
            }
            __syncthreads();
        }
        if (tid == 0) {   // dedup 22-bit prefixes
            int nu2 = 0;
            for (int k = 0; k < 4; ++k) {
                int fnd = -1;
                for (int u = 0; u < nu2; ++u) if (s_u[u] == s_pfx[k]) fnd = u;
                if (fnd < 0) { s_u[nu2] = s_pfx[k]; fnd = nu2; ++nu2; }
                s_slot[k] = fnd;
            }
            s_nu = nu2;
        }
        __syncthreads();
    }

    // ---- level 3: key&0x3FF within matched 22-bit prefixes ----
    {
        int nu = s_nu;
        for (int g = 0; g < nu; ++g) {
            for (int i = tid; i < 1024; i += 256) hist[i] = 0;
            __syncthreads();
            uint32_t u = s_u[g];
            for (uint32_t i = tid; i < n; i += 256) {
                uint32_t key = keys[i];
                if ((key >> 10) == u) atomicAdd(&hist[key & 0x3FFu], 1u);
            }
            __syncthreads();
            locate_ranks(hist, 4, s_rank, s_base, s_slot, g, 1, s_tbin, s_tbel, s_ws);
            if (tid == 0) {
                for (int k = 0; k < 4; ++k) if (s_slot[k] == g)
                    s_pfx[k] = (s_pfx[k] << 10) | s_tbin[k];
            }
            __syncthreads();
        }
        if (tid == 0) {
            float v[4];
            for (int k = 0; k < 4; ++k) v[k] = __uint_as_float(s_pfx[k]);
            float nf = (float)n;
            float pos1 = 0.25f * fmaxf(nf - 1.0f, 0.0f);
            float pos3 = 0.75f * fmaxf(nf - 1.0f, 0.0f);
            float f1 = pos1 - floorf(pos1);
            float f3 = pos3 - floorf(pos3);
            float q1 = v[0] + (v[1] - v[0]) * f1;
            float q3 = v[2] + (v[3] - v[2]) * f3;
            float iqr = q3 - q1;
            s_lbub[0] = q1 - 1.5f * iqr;
            s_lbub[1] = q3 + 1.5f * iqr;
        }
        __syncthreads();
    }

    // ---- compact from LDS list (early exit once K slots filled) ----
    const float lb = s_lbub[0], ub = s_lbub[1];
    uint32_t run = 0;
    for (uint32_t c0 = 0; c0 < n; c0 += 256) {
        uint32_t i = c0 + tid;
        bool keep = false;
        float d = 0.0f;
        uint32_t id = 0;
        if (i < n) {
            uint32_t key = keys[i];
            d = __uint_as_float(key);
            keep = (d >= lb) && (d <= ub);
            id = sidx[i];
        }
        uint32_t c = keep ? 1u : 0u;
        uint32_t incl = wave_incl_scan(c, lane);
        if (lane == 63) s_ws[wv] = incl;
        __syncthreads();
        uint32_t r = run + incl - c;
        for (int w = 0; w < wv; ++w) r += s_ws[w];
        uint32_t tot = s_ws[0] + s_ws[1] + s_ws[2] + s_ws[3];
        if (keep && r < KMAX) {
            uint32_t row = id / WID;
            uint32_t col = id - row * WID;
            outB[r] = xc_tab[col] * d;
            outB[STRIDE_C + r] = yc_tab[row] * d;
            outB[2 * STRIDE_C + r] = d;
        }
        run += tot;
        __syncthreads();   // protect s_ws for next chunk
        if (run >= KMAX) break;
    }
    uint32_t start = run < KMAX ? run : KMAX;
    for (uint32_t r = start + tid; r < KMAX; r += 256) {
        outB[r] = 0.f; outB[STRIDE_C + r] = 0.f; outB[2 * STRIDE_C + r] = 0.f;
    }
    if (tid == 0) {
        outB[KMAX] = (run > 0) ? 1.0f : 0.0f;
        outB[STRIDE_C + KMAX] = 0.f;
        outB[2 * STRIDE_C + KMAX] = 0.f;
    }
}

extern "C" void kernel_launch(void* const* d_in, const int* in_sizes, int n_in,
                              void* d_out, int out_size, void* d_ws, size_t ws_size,
                              hipStream_t stream) {
    (void)n_in; (void)out_size; (void)d_ws; (void)ws_size;
    const float* in = (const float*)d_in[0];
    float* out = (float*)d_out;
    const int B = in_sizes[0] / (3 * NPIX);
    fused<<<B * PMAX, 256, 0, stream>>>(in, out, B);
}

// Round 4
// 116.362 us; speedup vs baseline: 7.7965x; 1.3070x over previous
//
#include <hip/hip_runtime.h>
#include <math.h>

#define HGT 150
#define WID 200
#define NPIX 30000
#define NF4  7500           // NPIX/4
#define KMAX 1024
#define PMAX 5
#define CAP  4096           // LDS list capacity; n ~ 3125 +- 53 => 18 sigma margin
#define NW   938            // ceil(NPIX/32) kept-bitmask words
#define NBIN 1024
#define GCAP 128
#define STRIDE_C (PMAX*(KMAX+1))

__device__ __forceinline__ uint32_t wave_incl_scan(uint32_t x, int lane) {
#pragma unroll
    for (int off = 1; off < 64; off <<= 1) {
        uint32_t y = __shfl_up(x, (unsigned)off, 64);
        if (lane >= off) x += y;
    }
    return x;
}
__device__ __forceinline__ uint32_t wave_red_add(uint32_t x) {
#pragma unroll
    for (int off = 32; off >= 1; off >>= 1) x += __shfl_xor(x, off, 64);
    return x;
}
__device__ __forceinline__ uint32_t wave_red_min(uint32_t x) {
#pragma unroll
    for (int off = 32; off >= 1; off >>= 1) { uint32_t y = __shfl_xor(x, off, 64); x = y < x ? y : x; }
    return x;
}
__device__ __forceinline__ uint32_t wave_red_max(uint32_t x) {
#pragma unroll
    for (int off = 32; off >= 1; off >>= 1) { uint32_t y = __shfl_xor(x, off, 64); x = y > x ? y : x; }
    return x;
}

// Parallel rank-location in a histogram of 256*seg bins (validated R2/R3).
__device__ void locate_ranks(const uint32_t* hh, int seg,
                             const uint32_t* s_rank, const uint32_t* s_base,
                             uint32_t* s_tbin, uint32_t* s_tbel, uint32_t* s_ws) {
    const int tid = threadIdx.x, lane = tid & 63, wv = tid >> 6;
    const uint32_t* mine = hh + tid * seg;
    uint32_t segsum = 0;
    for (int j = 0; j < seg; ++j) segsum += mine[j];
    uint32_t inc = wave_incl_scan(segsum, lane);
    if (lane == 63) s_ws[wv] = inc;
    __syncthreads();
    uint32_t tbase = inc - segsum;
    for (int w = 0; w < wv; ++w) tbase += s_ws[w];
#pragma unroll
    for (int k = 0; k < 4; ++k) {
        uint32_t r = s_rank[k] - s_base[k];
        if (r >= tbase && r < tbase + segsum) {
            uint32_t c = tbase;
            for (int j = 0; j < seg; ++j) {
                uint32_t h = mine[j];
                if (r < c + h) { s_tbin[k] = (uint32_t)(tid * seg + j); s_tbel[k] = c; break; }
                c += h;
            }
        }
    }
    __syncthreads();
}

__global__ __launch_bounds__(256, 4) void fused(const float* __restrict__ in,
                                                float* __restrict__ out, int B) {
    // XCD-aware remap: same (blockIdx&7) -> same XCD; contiguous batch range per XCD.
    const int nbp = B * PMAX;
    int x = blockIdx.x, b, p;
    if ((nbp & 7) == 0) {
        int per = nbp >> 3;
        int slot = (x & 7) * per + (x >> 3);
        b = slot / PMAX; p = slot - b * PMAX;
    } else { b = x / PMAX; p = x - b * PMAX; }

    const float pid = (float)(p + 1);
    const float4* __restrict__ depth4 = (const float4*)(in + (size_t)b * 3 * NPIX);
    const float4* __restrict__ ind4   = depth4 + NF4;
    const int tid = threadIdx.x, lane = tid & 63, wv = tid >> 6;

    __shared__ uint32_t keys[CAP];          // 16 KB
    __shared__ unsigned short sidx[CAP];    //  8 KB
    __shared__ uint32_t hist[NBIN];         //  4 KB
    __shared__ uint32_t vb2[NW];            //  3.7 KB kept-pixel bitmask
    __shared__ unsigned short wpfx[NW];     //  1.9 KB per-word kept prefix
    __shared__ float xc_tab[WID];
    __shared__ float yc_tab[HGT];
    __shared__ uint32_t gbuf[4 * GCAP];     //  2 KB quantile gather
    __shared__ uint32_t gcnt[4];
    __shared__ uint32_t s_ws[4];
    __shared__ uint32_t s_mm[8];
    __shared__ uint32_t s_rank[4], s_base[4], s_tbin[4], s_tbel[4], s_u[4], s_val[4];
    __shared__ int s_slot[4], s_desc[4];
    __shared__ uint32_t s_dprefix, s_dr;
    __shared__ float s_lbub[2];

    // ---- init LDS + ray tables (double to match numpy float64 fx/fy) ----
    for (int i = tid; i < NBIN; i += 256) hist[i] = 0;
    for (int i = tid; i < NW; i += 256) vb2[i] = 0;
    {
        const double fxd = (double)WID / (2.0 * tan((81.0 * M_PI / 180.0) * 0.5));
        const double fyd = (double)HGT / (2.0 * tan((59.0 * M_PI / 180.0) * 0.5));
        for (int i = tid; i < WID; i += 256) xc_tab[i] = (float)(((double)i - (double)WID / 2.0) / fxd);
        for (int i = tid; i < HGT; i += 256) yc_tab[i] = (float)(((double)i - (double)HGT / 2.0) / fyd);
    }

    // ---- Phase A: coalesced load, validity nibbles, count, key min/max ----
    uint32_t m[4] = {0u, 0u, 0u, 0u};
    uint32_t cnt = 0, kmn = 0xFFFFFFFFu, kmx = 0u;
#pragma unroll 6
    for (int k = 0; k < 30; ++k) {
        int f = k * 256 + tid;
        if (f < NF4) {
            float4 d4 = depth4[f];
            float4 i4 = ind4[f];
            const float* dd = (const float*)&d4;
            const float* ii = (const float*)&i4;
            uint32_t nib = 0;
#pragma unroll
            for (int j = 0; j < 4; ++j)
                if (rintf(ii[j]) == pid && dd[j] > 3.0f) {
                    nib |= 1u << j;
                    uint32_t key = __float_as_uint(dd[j]);
                    kmn = key < kmn ? key : kmn;
                    kmx = key > kmx ? key : kmx;
                }
            cnt += (uint32_t)__popc(nib);
            m[k >> 3] |= nib << (4 * (k & 7));
        }
    }
    {
        uint32_t inc = wave_incl_scan(cnt, lane);
        uint32_t wmn = wave_red_min(kmn), wmx = wave_red_max(kmx);
        if (lane == 63) s_ws[wv] = inc;
        if (lane == 0) { s_mm[wv] = wmn; s_mm[4 + wv] = wmx; }
        __syncthreads();
        uint32_t bacc = inc - cnt;
        for (int w = 0; w < wv; ++w) bacc += s_ws[w];
        cnt = bacc;              // reuse: cnt = my base offset
        kmn = s_mm[0]; kmx = s_mm[4];
#pragma unroll
        for (int w = 1; w < 4; ++w) {
            kmn = s_mm[w] < kmn ? s_mm[w] : kmn;
            kmx = s_mm[4 + w] > kmx ? s_mm[4 + w] : kmx;
        }
    }
    const uint32_t n = s_ws[0] + s_ws[1] + s_ws[2] + s_ws[3];
    const uint32_t mybase = cnt;

    float* outB = out + (size_t)b * 3 * STRIDE_C + p * (KMAX + 1);

    if (n == 0) {   // uniform: empty -> all zeros incl. flag
        for (int r = tid; r <= KMAX; r += 256) {
            outB[r] = 0.f; outB[STRIDE_C + r] = 0.f; outB[2 * STRIDE_C + r] = 0.f;
        }
        return;
    }

    // rank targets (deterministic; computed by every thread)
    uint32_t rank[4]; float posf[2];
    {
        float nf = (float)n;
        posf[0] = 0.25f * fmaxf(nf - 1.0f, 0.0f);
        posf[1] = 0.75f * fmaxf(nf - 1.0f, 0.0f);
        rank[0] = (uint32_t)floorf(posf[0]); rank[1] = (uint32_t)ceilf(posf[0]);
        rank[2] = (uint32_t)floorf(posf[1]); rank[3] = (uint32_t)ceilf(posf[1]);
    }

    if (n > CAP) {
        // ---- correctness-only fallback: block-parallel bit descent on global ----
        uint32_t v[4];
        for (int k = 0; k < 4; ++k) {
            if (tid == 0) { s_dprefix = 0; s_dr = rank[k]; }
            __syncthreads();
            for (int bit = 30; bit >= 0; --bit) {
                uint32_t pfx = s_dprefix;
                uint32_t c = 0;
                for (int kk = 0; kk < 30; ++kk) {
                    int f = kk * 256 + tid;
                    if (f < NF4) {
                        float4 d4 = depth4[f]; float4 i4 = ind4[f];
                        const float* dd = (const float*)&d4;
                        const float* ii = (const float*)&i4;
#pragma unroll
                        for (int j = 0; j < 4; ++j)
                            if (rintf(ii[j]) == pid && dd[j] > 3.0f) {
                                uint32_t key = __float_as_uint(dd[j]);
                                if ((key >> (bit + 1)) == pfx && !((key >> bit) & 1u)) ++c;
                            }
                    }
                }
                c = wave_red_add(c);
                if (lane == 0) s_ws[wv] = c;
                __syncthreads();
                uint32_t c0 = s_ws[0] + s_ws[1] + s_ws[2] + s_ws[3];
                if (tid == 0) {
                    if (s_dr < c0) s_dprefix = pfx << 1;
                    else { s_dprefix = (pfx << 1) | 1u; s_dr -= c0; }
                }
                __syncthreads();
            }
            v[k] = s_dprefix;
            __syncthreads();
        }
        float f1 = posf[0] - floorf(posf[0]);
        float f3 = posf[1] - floorf(posf[1]);
        float q1 = __uint_as_float(v[0]) + (__uint_as_float(v[1]) - __uint_as_float(v[0])) * f1;
        float q3 = __uint_as_float(v[2]) + (__uint_as_float(v[3]) - __uint_as_float(v[2])) * f3;
        float iqr = q3 - q1;
        float lb = q1 - 1.5f * iqr, ub = q3 + 1.5f * iqr;
        if (tid == 0) {
            const float* depth = (const float*)depth4;
            const float* ind = (const float*)ind4;
            uint32_t r = 0;
            for (int i = 0; i < NPIX; ++i) {
                float d = depth[i];
                if (rintf(ind[i]) == pid && d > 3.0f && d >= lb && d <= ub) {
                    if (r < KMAX) {
                        int row = i / WID, col = i - row * WID;
                        outB[r] = xc_tab[col] * d;
                        outB[STRIDE_C + r] = yc_tab[row] * d;
                        outB[2 * STRIDE_C + r] = d;
                    }
                    ++r;
                }
            }
            s_dr = r;
        }
        __syncthreads();
        uint32_t count = s_dr;
        uint32_t start = count < KMAX ? count : KMAX;
        for (uint32_t r = start + tid; r < KMAX; r += 256) {
            outB[r] = 0.f; outB[STRIDE_C + r] = 0.f; outB[2 * STRIDE_C + r] = 0.f;
        }
        if (tid == 0) {
            outB[KMAX] = (count > 0) ? 1.0f : 0.0f;
            outB[STRIDE_C + KMAX] = 0.f; outB[2 * STRIDE_C + KMAX] = 0.f;
        }
        return;
    }

    // ---- Phase B: replay -> (key, sidx) list in LDS (list order arbitrary) ----
    {
        uint32_t pos = mybase;
#pragma unroll 6
        for (int k = 0; k < 30; ++k) {
            uint32_t nib = (m[k >> 3] >> (4 * (k & 7))) & 0xFu;
            if (nib) {
                int f = k * 256 + tid;
                float4 d4 = depth4[f];
                const float* dd = (const float*)&d4;
#pragma unroll
                for (int j = 0; j < 4; ++j)
                    if ((nib >> j) & 1u) {
                        keys[pos] = __float_as_uint(dd[j]);
                        sidx[pos] = (unsigned short)(f * 4 + j);
                        ++pos;
                    }
            }
        }
        if (tid == 0) {
#pragma unroll
            for (int k = 0; k < 4; ++k) { s_rank[k] = rank[k]; s_base[k] = 0; }
        }
        __syncthreads();
    }

    // ---- quantiles: single linear 1024-bin histogram + gather-select ----
    const uint32_t span = kmx - kmn;
    const bool exact = (span < NBIN);                 // identity binning: 1 value/bin
    uint32_t scale = 0;
    if (!exact) scale = (uint32_t)(((uint64_t)NBIN << 32) / ((uint64_t)span + 1));

    for (uint32_t i = tid; i < n; i += 256) {
        uint32_t key = keys[i];
        uint32_t bin = exact ? (key - kmn)
                             : (uint32_t)(((uint64_t)(key - kmn) * scale) >> 32);
        atomicAdd(&hist[bin], 1u);
    }
    __syncthreads();
    locate_ranks(hist, NBIN / 256, s_rank, s_base, s_tbin, s_tbel, s_ws);

    if (tid == 0) {
        if (exact) {
#pragma unroll
            for (int k = 0; k < 4; ++k) s_val[k] = kmn + s_tbin[k];
        } else {
            uint32_t uq[4]; int nu = 0;
#pragma unroll
            for (int k = 0; k < 4; ++k) {
                s_base[k] = s_tbel[k];
                int fnd = -1;
                for (int u = 0; u < nu; ++u) if (uq[u] == s_tbin[k]) fnd = u;
                if (fnd < 0) { uq[nu] = s_tbin[k]; fnd = nu; ++nu; }
                s_slot[k] = fnd;
            }
#pragma unroll
            for (int u = 0; u < 4; ++u) { s_u[u] = 0xFFFFFFFFu; gcnt[u] = 0; }
            for (int u = 0; u < nu; ++u) if (hist[uq[u]] <= GCAP) s_u[u] = uq[u];
#pragma unroll
            for (int k = 0; k < 4; ++k) s_desc[k] = (hist[uq[s_slot[k]]] > GCAP) ? 1 : 0;
        }
    }
    __syncthreads();

    if (!exact) {
        // gather candidates for the <=4 unique target bins
        for (uint32_t i = tid; i < n; i += 256) {
            uint32_t key = keys[i];
            uint32_t bin = (uint32_t)(((uint64_t)(key - kmn) * scale) >> 32);
#pragma unroll
            for (int u = 0; u < 4; ++u)
                if (bin == s_u[u]) {
                    uint32_t slot = atomicAdd(&gcnt[u], 1u);
                    if (slot < GCAP) gbuf[u * GCAP + slot] = key;
                }
        }
        __syncthreads();
        // select: wave k resolves rank k by counting within its gathered bin
        if (wv < 4 && !s_desc[wv]) {
            int u = s_slot[wv];
            uint32_t c = gcnt[u];
            uint32_t res = s_rank[wv] - s_base[wv];
            for (uint32_t i = lane; i < c; i += 64) {
                uint32_t xk = gbuf[u * GCAP + i];
                uint32_t less = 0, eq = 0;
                for (uint32_t j = 0; j < c; ++j) {
                    uint32_t y = gbuf[u * GCAP + j];
                    less += (y < xk); eq += (y == xk);
                }
                if (res >= less && res < less + eq) s_val[wv] = xk;
            }
        }
        __syncthreads();
        // rare exact fallback: bitwise radix descent over the LDS list
        for (int k = 0; k < 4; ++k) if (s_desc[k]) {
            if (tid == 0) { s_dprefix = 0; s_dr = s_rank[k]; }
            __syncthreads();
            for (int bit = 30; bit >= 0; --bit) {
                uint32_t pfx = s_dprefix;
                uint32_t c = 0;
                for (uint32_t i = tid; i < n; i += 256) {
                    uint32_t key = keys[i];
                    if ((key >> (bit + 1)) == pfx && !((key >> bit) & 1u)) ++c;
                }
                c = wave_red_add(c);
                if (lane == 0) s_ws[wv] = c;
                __syncthreads();
                uint32_t c0 = s_ws[0] + s_ws[1] + s_ws[2] + s_ws[3];
                if (tid == 0) {
                    if (s_dr < c0) s_dprefix = pfx << 1;
                    else { s_dprefix = (pfx << 1) | 1u; s_dr -= c0; }
                }
                __syncthreads();
            }
            if (tid == 0) s_val[k] = s_dprefix;
            __syncthreads();
        }
    }

    if (tid == 0) {
        float f1 = posf[0] - floorf(posf[0]);
        float f3 = posf[1] - floorf(posf[1]);
        float v0 = __uint_as_float(s_val[0]), v1 = __uint_as_float(s_val[1]);
        float v2 = __uint_as_float(s_val[2]), v3 = __uint_as_float(s_val[3]);
        float q1 = v0 + (v1 - v0) * f1;
        float q3 = v2 + (v3 - v2) * f3;
        float iqr = q3 - q1;
        s_lbub[0] = q1 - 1.5f * iqr;
        s_lbub[1] = q3 + 1.5f * iqr;
    }
    __syncthreads();

    // ---- kept-bitmask + prefix -> raster ranks without chunked barriers ----
    const float lb = s_lbub[0], ub = s_lbub[1];
    for (uint32_t i = tid; i < n; i += 256) {
        float d = __uint_as_float(keys[i]);
        if (d >= lb && d <= ub) {
            int s = sidx[i];
            atomicOr(&vb2[s >> 5], 1u << (s & 31));
        }
    }
    __syncthreads();
    uint32_t pc[4] = {0, 0, 0, 0};
    uint32_t lsum = 0;
    const int w0 = tid * 4;
#pragma unroll
    for (int j = 0; j < 4; ++j)
        if (w0 + j < NW) { pc[j] = (uint32_t)__popc(vb2[w0 + j]); lsum += pc[j]; }
    {
        uint32_t inc = wave_incl_scan(lsum, lane);
        if (lane == 63) s_ws[wv] = inc;
        __syncthreads();
        uint32_t tb = inc - lsum;
        for (int w = 0; w < wv; ++w) tb += s_ws[w];
        uint32_t run = tb;
#pragma unroll
        for (int j = 0; j < 4; ++j)
            if (w0 + j < NW) { wpfx[w0 + j] = (unsigned short)run; run += pc[j]; }
    }
    __syncthreads();
    const uint32_t total = s_ws[0] + s_ws[1] + s_ws[2] + s_ws[3];

    // ---- output: rank from bitmask prefix, single parallel pass ----
    for (uint32_t i = tid; i < n; i += 256) {
        uint32_t key = keys[i];
        float d = __uint_as_float(key);
        if (d >= lb && d <= ub) {
            int s = sidx[i];
            int w = s >> 5;
            uint32_t r = (uint32_t)wpfx[w] + (uint32_t)__popc(vb2[w] & ((1u << (s & 31)) - 1u));
            if (r < KMAX) {
                int row = s / WID;
                int col = s - row * WID;
                outB[r] = xc_tab[col] * d;
                outB[STRIDE_C + r] = yc_tab[row] * d;
                outB[2 * STRIDE_C + r] = d;
            }
        }
    }
    uint32_t start = total < KMAX ? total : KMAX;
    for (uint32_t r = start + tid; r < KMAX; r += 256) {
        outB[r] = 0.f; outB[STRIDE_C + r] = 0.f; outB[2 * STRIDE_C + r] = 0.f;
    }
    if (tid == 0) {
        outB[KMAX] = (total > 0) ? 1.0f : 0.0f;
        outB[STRIDE_C + KMAX] = 0.f;
        outB[2 * STRIDE_C + KMAX] = 0.f;
    }
}

extern "C" void kernel_launch(void* const* d_in, const int* in_sizes, int n_in,
                              void* d_out, int out_size, void* d_ws, size_t ws_size,
                              hipStream_t stream) {
    (void)n_in; (void)out_size; (void)d_ws; (void)ws_size;
    const float* in = (const float*)d_in[0];
    float* out = (float*)d_out;
    const int B = in_sizes[0] / (3 * NPIX);
    fused<<<B * PMAX, 256, 0, stream>>>(in, out, B);
}

// Round 5
// 101.519 us; speedup vs baseline: 8.9365x; 1.1462x over previous
//
#include <hip/hip_runtime.h>
#include <math.h>

#define HGT 150
#define WID 200
#define NPIX 30000
#define NF4  7500            // NPIX/4
#define KMAX 1024
#define PMAX 5
#define THREADS 512
#define NWAVES 8
#define CAP  4096            // list capacity; n ~ 3125 +- 53 => 18 sigma margin
#define NWORDS 938           // ceil(NPIX/32)
#define NWPAD 940            // padded to uint4 multiple
#define NBIN 2048
#define SHIFT 13             // bin = (key - bits(3.0)) >> 13, monotone, ~2 keys/bin
#define KBASE 0x40400000u    // bits(3.0f); valid keys strictly greater (d > 3.0)
#define GCAP 128
#define STRIDE_C (PMAX*(KMAX+1))

__device__ __forceinline__ uint32_t wave_incl_scan(uint32_t x, int lane) {
#pragma unroll
    for (int off = 1; off < 64; off <<= 1) {
        uint32_t y = __shfl_up(x, (unsigned)off, 64);
        if (lane >= off) x += y;
    }
    return x;
}
__device__ __forceinline__ uint32_t wave_red_add(uint32_t x) {
#pragma unroll
    for (int off = 32; off >= 1; off >>= 1) x += __shfl_xor(x, off, 64);
    return x;
}
__device__ __forceinline__ uint32_t key_bin(uint32_t key) {
    uint32_t d = (key - KBASE) >> SHIFT;     // key > KBASE always (depth > 3.0)
    return d < NBIN ? d : (NBIN - 1);        // clamp bin stays monotone
}

// Parallel rank-location in a histogram of THREADS*seg bins (validated R2-R4).
// s_tbel[k] = count of elements strictly below bin s_tbin[k].
__device__ void locate_ranks(const uint32_t* hh, int seg, const uint32_t* s_rank,
                             uint32_t* s_tbin, uint32_t* s_tbel, uint32_t* s_ws) {
    const int tid = threadIdx.x, lane = tid & 63, wv = tid >> 6;
    const uint32_t* mine = hh + tid * seg;
    uint32_t segsum = 0;
    for (int j = 0; j < seg; ++j) segsum += mine[j];
    uint32_t inc = wave_incl_scan(segsum, lane);
    if (lane == 63) s_ws[wv] = inc;
    __syncthreads();
    uint32_t tbase = inc - segsum;
    for (int w = 0; w < wv; ++w) tbase += s_ws[w];
#pragma unroll
    for (int k = 0; k < 4; ++k) {
        uint32_t r = s_rank[k];
        if (r >= tbase && r < tbase + segsum) {
            uint32_t c = tbase;
            for (int j = 0; j < seg; ++j) {
                uint32_t h = mine[j];
                if (r < c + h) { s_tbin[k] = (uint32_t)(tid * seg + j); s_tbel[k] = c; break; }
                c += h;
            }
        }
    }
    __syncthreads();
}

__global__ __launch_bounds__(THREADS, 4) void fused(const float* __restrict__ in,
                                                    float* __restrict__ out, int B) {
    // XCD-aware remap: same (blockIdx&7) -> same XCD; contiguous batch range per XCD.
    const int nbp = B * PMAX;
    int x = blockIdx.x, b, p;
    if ((nbp & 7) == 0) {
        int per = nbp >> 3;
        int slot = (x & 7) * per + (x >> 3);
        b = slot / PMAX; p = slot - b * PMAX;
    } else { b = x / PMAX; p = x - b * PMAX; }

    const float pid = (float)(p + 1);
    const float4* __restrict__ depth4 = (const float4*)(in + (size_t)b * 3 * NPIX);
    const float4* __restrict__ ind4   = depth4 + NF4;
    const int tid = threadIdx.x, lane = tid & 63, wv = tid >> 6;

    __shared__ uint2 list[CAP];             // 32 KB  (key, pixel idx)
    __shared__ uint32_t hist[NBIN];         //  8 KB
    __shared__ uint32_t vb2[NWPAD];         //  3.76 KB kept-pixel bitmask
    __shared__ unsigned short wpfx[NWPAD];  //  1.88 KB per-word kept prefix
    __shared__ float xc_tab[WID];
    __shared__ float yc_tab[HGT];
    __shared__ uint32_t gbuf[4 * GCAP];     //  2 KB quantile gather
    __shared__ uint32_t gcnt[4];
    __shared__ uint32_t s_ws[NWAVES];
    __shared__ uint32_t s_rank[4], s_res[4], s_tbin[4], s_tbel[4], s_u[4], s_val[4];
    __shared__ int s_slot[4], s_desc[4];
    __shared__ uint32_t s_cnt, s_dprefix, s_dr;
    __shared__ float s_lbub[2];

    // ---- init LDS + ray tables (double to match numpy float64 fx/fy) ----
    for (int i = tid; i < NBIN; i += THREADS) hist[i] = 0;
    for (int i = tid; i < NWPAD; i += THREADS) vb2[i] = 0;
    if (tid == 0) s_cnt = 0;
    {
        const double fxd = (double)WID / (2.0 * tan((81.0 * M_PI / 180.0) * 0.5));
        const double fyd = (double)HGT / (2.0 * tan((59.0 * M_PI / 180.0) * 0.5));
        for (int i = tid; i < WID; i += THREADS) xc_tab[i] = (float)(((double)i - (double)WID / 2.0) / fxd);
        for (int i = tid; i < HGT; i += THREADS) yc_tab[i] = (float)(((double)i - (double)HGT / 2.0) / fyd);
    }
    __syncthreads();

    // ---- Phase A (single global pass): validate, histogram, append to list ----
#pragma unroll 5
    for (int k = 0; k < 15; ++k) {
        int f = k * THREADS + tid;
        uint32_t nib = 0;
        float4 d4;
        if (f < NF4) {
            d4 = depth4[f];
            float4 i4 = ind4[f];
            const float* dd = (const float*)&d4;
            const float* ii = (const float*)&i4;
#pragma unroll
            for (int j = 0; j < 4; ++j)
                if (rintf(ii[j]) == pid && dd[j] > 3.0f) nib |= 1u << j;
        }
        uint32_t cnt_t = (uint32_t)__popc(nib);
        uint32_t incl = wave_incl_scan(cnt_t, lane);
        uint32_t wtot = __shfl(incl, 63, 64);
        uint32_t base = 0;
        if (lane == 63 && wtot) base = atomicAdd(&s_cnt, wtot);
        base = __shfl(base, 63, 64);
        uint32_t pos = base + incl - cnt_t;
        if (nib) {
            const float* dd = (const float*)&d4;
#pragma unroll
            for (int j = 0; j < 4; ++j)
                if ((nib >> j) & 1u) {
                    uint32_t key = __float_as_uint(dd[j]);
                    atomicAdd(&hist[key_bin(key)], 1u);
                    if (pos < CAP) list[pos] = make_uint2(key, (uint32_t)(f * 4 + j));
                    ++pos;
                }
        }
    }
    __syncthreads();
    const uint32_t n = s_cnt;

    float* outB = out + (size_t)b * 3 * STRIDE_C + p * (KMAX + 1);

    if (n == 0) {   // uniform: empty -> all zeros incl. flag
        for (int r = tid; r <= KMAX; r += THREADS) {
            outB[r] = 0.f; outB[STRIDE_C + r] = 0.f; outB[2 * STRIDE_C + r] = 0.f;
        }
        return;
    }

    // rank targets (deterministic; computed by every thread)
    uint32_t rank[4]; float posf[2];
    {
        float nf = (float)n;
        posf[0] = 0.25f * fmaxf(nf - 1.0f, 0.0f);
        posf[1] = 0.75f * fmaxf(nf - 1.0f, 0.0f);
        rank[0] = (uint32_t)floorf(posf[0]); rank[1] = (uint32_t)ceilf(posf[0]);
        rank[2] = (uint32_t)floorf(posf[1]); rank[3] = (uint32_t)ceilf(posf[1]);
    }

    if (n > CAP) {
        // ---- correctness-only fallback: block-parallel bit descent on global ----
        uint32_t v[4];
        for (int k = 0; k < 4; ++k) {
            if (tid == 0) { s_dprefix = 0; s_dr = rank[k]; }
            __syncthreads();
            for (int bit = 30; bit >= 0; --bit) {
                uint32_t pfx = s_dprefix;
                uint32_t c = 0;
                for (int kk = 0; kk < 15; ++kk) {
                    int f = kk * THREADS + tid;
                    if (f < NF4) {
                        float4 d4 = depth4[f]; float4 i4 = ind4[f];
                        const float* dd = (const float*)&d4;
                        const float* ii = (const float*)&i4;
#pragma unroll
                        for (int j = 0; j < 4; ++j)
                            if (rintf(ii[j]) == pid && dd[j] > 3.0f) {
                                uint32_t key = __float_as_uint(dd[j]);
                                if ((key >> (bit + 1)) == pfx && !((key >> bit) & 1u)) ++c;
                            }
                    }
                }
                c = wave_red_add(c);
                if (lane == 0) s_ws[wv] = c;
                __syncthreads();
                uint32_t c0 = 0;
                for (int w = 0; w < NWAVES; ++w) c0 += s_ws[w];
                if (tid == 0) {
                    if (s_dr < c0) s_dprefix = pfx << 1;
                    else { s_dprefix = (pfx << 1) | 1u; s_dr -= c0; }
                }
                __syncthreads();
            }
            v[k] = s_dprefix;
            __syncthreads();
        }
        float f1 = posf[0] - floorf(posf[0]);
        float f3 = posf[1] - floorf(posf[1]);
        float q1 = __uint_as_float(v[0]) + (__uint_as_float(v[1]) - __uint_as_float(v[0])) * f1;
        float q3 = __uint_as_float(v[2]) + (__uint_as_float(v[3]) - __uint_as_float(v[2])) * f3;
        float iqr = q3 - q1;
        float lb = q1 - 1.5f * iqr, ub = q3 + 1.5f * iqr;
        if (tid == 0) {
            const float* depth = (const float*)depth4;
            const float* ind = (const float*)ind4;
            uint32_t r = 0;
            for (int i = 0; i < NPIX; ++i) {
                float d = depth[i];
                if (rintf(ind[i]) == pid && d > 3.0f && d >= lb && d <= ub) {
                    if (r < KMAX) {
                        int row = i / WID, col = i - row * WID;
                        outB[r] = xc_tab[col] * d;
                        outB[STRIDE_C + r] = yc_tab[row] * d;
                        outB[2 * STRIDE_C + r] = d;
                    }
                    ++r;
                }
            }
            s_dr = r;
        }
        __syncthreads();
        uint32_t count = s_dr;
        uint32_t start = count < KMAX ? count : KMAX;
        for (uint32_t r = start + tid; r < KMAX; r += THREADS) {
            outB[r] = 0.f; outB[STRIDE_C + r] = 0.f; outB[2 * STRIDE_C + r] = 0.f;
        }
        if (tid == 0) {
            outB[KMAX] = (count > 0) ? 1.0f : 0.0f;
            outB[STRIDE_C + KMAX] = 0.f; outB[2 * STRIDE_C + KMAX] = 0.f;
        }
        return;
    }

    // ---- locate rank bins in the fixed-base histogram ----
    if (tid == 0) {
#pragma unroll
        for (int k = 0; k < 4; ++k) s_rank[k] = rank[k];
    }
    __syncthreads();
    locate_ranks(hist, NBIN / THREADS, s_rank, s_tbin, s_tbel, s_ws);

    if (tid == 0) {
        uint32_t uq[4]; int nu = 0;
#pragma unroll
        for (int k = 0; k < 4; ++k) {
            s_res[k] = rank[k] - s_tbel[k];
            int fnd = -1;
            for (int u = 0; u < nu; ++u) if (uq[u] == s_tbin[k]) fnd = u;
            if (fnd < 0) { uq[nu] = s_tbin[k]; fnd = nu; ++nu; }
            s_slot[k] = fnd;
        }
#pragma unroll
        for (int u = 0; u < 4; ++u) { s_u[u] = 0xFFFFFFFFu; gcnt[u] = 0; }
        for (int u = 0; u < nu; ++u) if (hist[uq[u]] <= GCAP) s_u[u] = uq[u];
#pragma unroll
        for (int k = 0; k < 4; ++k) s_desc[k] = (hist[uq[s_slot[k]]] > GCAP) ? 1 : 0;
    }
    __syncthreads();

    // ---- gather candidates for the <=4 unique target bins ----
    for (uint32_t i = tid; i < n; i += THREADS) {
        uint32_t key = list[i].x;
        uint32_t bin = key_bin(key);
#pragma unroll
        for (int u = 0; u < 4; ++u)
            if (bin == s_u[u]) {
                uint32_t slot = atomicAdd(&gcnt[u], 1u);
                if (slot < GCAP) gbuf[u * GCAP + slot] = key;
            }
    }
    __syncthreads();
    // select: wave k resolves rank k by counting within its gathered bin
    if (wv < 4 && !s_desc[wv]) {
        int u = s_slot[wv];
        uint32_t c = gcnt[u];
        uint32_t res = s_res[wv];
        for (uint32_t i = lane; i < c; i += 64) {
            uint32_t xk = gbuf[u * GCAP + i];
            uint32_t less = 0, eq = 0;
            for (uint32_t j = 0; j < c; ++j) {
                uint32_t y = gbuf[u * GCAP + j];
                less += (y < xk); eq += (y == xk);
            }
            if (res >= less && res < less + eq) s_val[wv] = xk;
        }
    }
    __syncthreads();
    // rare exact fallback: bitwise radix descent over the LDS list
    for (int k = 0; k < 4; ++k) if (s_desc[k]) {
        if (tid == 0) { s_dprefix = 0; s_dr = rank[k]; }
        __syncthreads();
        for (int bit = 30; bit >= 0; --bit) {
            uint32_t pfx = s_dprefix;
            uint32_t c = 0;
            for (uint32_t i = tid; i < n; i += THREADS) {
                uint32_t key = list[i].x;
                if ((key >> (bit + 1)) == pfx && !((key >> bit) & 1u)) ++c;
            }
            c = wave_red_add(c);
            if (lane == 0) s_ws[wv] = c;
            __syncthreads();
            uint32_t c0 = 0;
            for (int w = 0; w < NWAVES; ++w) c0 += s_ws[w];
            if (tid == 0) {
                if (s_dr < c0) s_dprefix = pfx << 1;
                else { s_dprefix = (pfx << 1) | 1u; s_dr -= c0; }
            }
            __syncthreads();
        }
        if (tid == 0) s_val[k] = s_dprefix;
        __syncthreads();
    }

    if (tid == 0) {
        float f1 = posf[0] - floorf(posf[0]);
        float f3 = posf[1] - floorf(posf[1]);
        float v0 = __uint_as_float(s_val[0]), v1 = __uint_as_float(s_val[1]);
        float v2 = __uint_as_float(s_val[2]), v3 = __uint_as_float(s_val[3]);
        float q1 = v0 + (v1 - v0) * f1;
        float q3 = v2 + (v3 - v2) * f3;
        float iqr = q3 - q1;
        s_lbub[0] = q1 - 1.5f * iqr;
        s_lbub[1] = q3 + 1.5f * iqr;
    }
    __syncthreads();

    // ---- kept-bitmask -> raster ranks ----
    const float lb = s_lbub[0], ub = s_lbub[1];
    for (uint32_t i = tid; i < n; i += THREADS) {
        uint2 e = list[i];
        float d = __uint_as_float(e.x);
        if (d >= lb && d <= ub) atomicOr(&vb2[e.y >> 5], 1u << (e.y & 31));
    }
    __syncthreads();
    // per-word prefix via one conflict-free uint4 read per thread
    {
        uint4 v4 = make_uint4(0, 0, 0, 0);
        if (tid < NWPAD / 4) v4 = ((const uint4*)vb2)[tid];
        uint32_t pc0 = (uint32_t)__popc(v4.x), pc1 = (uint32_t)__popc(v4.y);
        uint32_t pc2 = (uint32_t)__popc(v4.z), pc3 = (uint32_t)__popc(v4.w);
        uint32_t lsum = pc0 + pc1 + pc2 + pc3;
        uint32_t inc = wave_incl_scan(lsum, lane);
        if (lane == 63) s_ws[wv] = inc;
        __syncthreads();
        uint32_t run = inc - lsum;
        for (int w = 0; w < wv; ++w) run += s_ws[w];
        if (tid < NWPAD / 4) {
            ushort4 w4;
            w4.x = (unsigned short)run;            run += pc0;
            w4.y = (unsigned short)run;            run += pc1;
            w4.z = (unsigned short)run;            run += pc2;
            w4.w = (unsigned short)run;
            ((ushort4*)wpfx)[tid] = w4;
        }
    }
    __syncthreads();
    uint32_t total = 0;
    for (int w = 0; w < NWAVES; ++w) total += s_ws[w];

    // ---- output: rank from bitmask prefix, single parallel pass ----
    for (uint32_t i = tid; i < n; i += THREADS) {
        uint2 e = list[i];
        float d = __uint_as_float(e.x);
        if (d >= lb && d <= ub) {
            uint32_t s = e.y;
            uint32_t w = s >> 5;
            uint32_t r = (uint32_t)wpfx[w] + (uint32_t)__popc(vb2[w] & ((1u << (s & 31)) - 1u));
            if (r < KMAX) {
                uint32_t row = s / WID;
                uint32_t col = s - row * WID;
                outB[r] = xc_tab[col] * d;
                outB[STRIDE_C + r] = yc_tab[row] * d;
                outB[2 * STRIDE_C + r] = d;
            }
        }
    }
    uint32_t start = total < KMAX ? total : KMAX;
    for (uint32_t r = start + tid; r < KMAX; r += THREADS) {
        outB[r] = 0.f; outB[STRIDE_C + r] = 0.f; outB[2 * STRIDE_C + r] = 0.f;
    }
    if (tid == 0) {
        outB[KMAX] = (total > 0) ? 1.0f : 0.0f;
        outB[STRIDE_C + KMAX] = 0.f;
        outB[2 * STRIDE_C + KMAX] = 0.f;
    }
}

extern "C" void kernel_launch(void* const* d_in, const int* in_sizes, int n_in,
                              void* d_out, int out_size, void* d_ws, size_t ws_size,
                              hipStream_t stream) {
    (void)n_in; (void)out_size; (void)d_ws; (void)ws_size;
    const float* in = (const float*)d_in[0];
    float* out = (float*)d_out;
    const int B = in_sizes[0] / (3 * NPIX);
    fused<<<B * PMAX, THREADS, 0, stream>>>(in, out, B);
}

// Round 6
// 100.018 us; speedup vs baseline: 9.0705x; 1.0150x over previous
//
#include <hip/hip_runtime.h>
#include <math.h>

#define HGT 150
#define WID 200
#define NPIX 30000
#define NF4  7500            // NPIX/4
#define KMAX 1024
#define PMAX 5
#define THREADS 512
#define NWAVES 8
#define CAPW 512             // per-wave list capacity; n/wave ~391 +- 20 => 6 sigma
#define CAP  (NWAVES*CAPW)
#define NWORDS 938           // ceil(NPIX/32)
#define NWPAD 940            // padded to uint4 multiple
#define NBIN 2048
#define SHIFT 13             // bin = (key - bits(3.0)) >> 13, monotone, ~2 keys/bin
#define KBASE 0x40400000u    // bits(3.0f); valid keys strictly greater (d > 3.0)
#define GCAP 128
#define STRIDE_C (PMAX*(KMAX+1))

__device__ __forceinline__ uint32_t wave_incl_scan(uint32_t x, int lane) {
#pragma unroll
    for (int off = 1; off < 64; off <<= 1) {
        uint32_t y = __shfl_up(x, (unsigned)off, 64);
        if (lane >= off) x += y;
    }
    return x;
}
__device__ __forceinline__ uint32_t wave_red_add(uint32_t x) {
#pragma unroll
    for (int off = 32; off >= 1; off >>= 1) x += __shfl_xor(x, off, 64);
    return x;
}
__device__ __forceinline__ uint32_t key_bin(uint32_t key) {
    uint32_t d = (key - KBASE) >> SHIFT;     // key > KBASE always (depth > 3.0)
    return d < NBIN ? d : (NBIN - 1);        // clamp bin stays monotone
}

// Parallel rank-location in a histogram of THREADS*seg bins (validated R2-R5).
// s_tbel[k] = count of elements strictly below bin s_tbin[k].
__device__ void locate_ranks(const uint32_t* hh, int seg, const uint32_t* s_rank,
                             uint32_t* s_tbin, uint32_t* s_tbel, uint32_t* s_ws) {
    const int tid = threadIdx.x, lane = tid & 63, wv = tid >> 6;
    const uint32_t* mine = hh + tid * seg;
    uint32_t segsum = 0;
    for (int j = 0; j < seg; ++j) segsum += mine[j];
    uint32_t inc = wave_incl_scan(segsum, lane);
    if (lane == 63) s_ws[wv] = inc;
    __syncthreads();
    uint32_t tbase = inc - segsum;
    for (int w = 0; w < wv; ++w) tbase += s_ws[w];
#pragma unroll
    for (int k = 0; k < 4; ++k) {
        uint32_t r = s_rank[k];
        if (r >= tbase && r < tbase + segsum) {
            uint32_t c = tbase;
            for (int j = 0; j < seg; ++j) {
                uint32_t h = mine[j];
                if (r < c + h) { s_tbin[k] = (uint32_t)(tid * seg + j); s_tbel[k] = c; break; }
                c += h;
            }
        }
    }
    __syncthreads();
}

__global__ __launch_bounds__(THREADS, 4) void fused(const float* __restrict__ in,
                                                    float* __restrict__ out, int B) {
    // XCD-aware remap: same (blockIdx&7) -> same XCD; contiguous batch range per XCD.
    const int nbp = B * PMAX;
    int x = blockIdx.x, b, p;
    if ((nbp & 7) == 0) {
        int per = nbp >> 3;
        int slot = (x & 7) * per + (x >> 3);
        b = slot / PMAX; p = slot - b * PMAX;
    } else { b = x / PMAX; p = x - b * PMAX; }

    const float pid = (float)(p + 1);
    const float4* __restrict__ depth4 = (const float4*)(in + (size_t)b * 3 * NPIX);
    const float4* __restrict__ ind4   = depth4 + NF4;
    const int tid = threadIdx.x, lane = tid & 63, wv = tid >> 6;

    __shared__ uint2 list[CAP];             // 32 KB  (key, pixel idx), 8 wave segments
    __shared__ uint32_t hist[NBIN];         //  8 KB
    __shared__ uint32_t vb2[NWPAD];         //  3.76 KB kept-pixel bitmask
    __shared__ unsigned short wpfx[NWPAD];  //  1.88 KB per-word kept prefix
    __shared__ float xc_tab[WID];
    __shared__ float yc_tab[HGT];
    __shared__ uint32_t gbuf[4 * GCAP];     //  2 KB quantile gather
    __shared__ uint32_t gcnt[4];
    __shared__ uint32_t s_ws[NWAVES];
    __shared__ uint32_t s_wcnt[NWAVES];
    __shared__ uint32_t s_rank[4], s_res[4], s_tbin[4], s_tbel[4], s_u[4], s_val[4];
    __shared__ int s_slot[4], s_desc[4];
    __shared__ uint32_t s_dprefix, s_dr;

    // ---- init LDS + ray tables (double to match numpy float64 fx/fy) ----
    for (int i = tid; i < NBIN; i += THREADS) hist[i] = 0;
    for (int i = tid; i < NWPAD; i += THREADS) vb2[i] = 0;
    {
        const double fxd = (double)WID / (2.0 * tan((81.0 * M_PI / 180.0) * 0.5));
        const double fyd = (double)HGT / (2.0 * tan((59.0 * M_PI / 180.0) * 0.5));
        for (int i = tid; i < WID; i += THREADS) xc_tab[i] = (float)(((double)i - (double)WID / 2.0) / fxd);
        for (int i = tid; i < HGT; i += THREADS) yc_tab[i] = (float)(((double)i - (double)HGT / 2.0) / fyd);
    }
    __syncthreads();

    // ---- Phase A (single global pass): validate, histogram, per-wave append ----
    // Wave-private segment + register running count: no cross-wave LDS atomics.
    const uint32_t segbase = (uint32_t)wv * CAPW;
    const uint32_t seglim = segbase + CAPW;
    uint32_t run = 0;
#pragma unroll 5
    for (int k = 0; k < 15; ++k) {
        int f = k * THREADS + tid;
        uint32_t nib = 0;
        float4 d4;
        if (f < NF4) {
            d4 = depth4[f];
            float4 i4 = ind4[f];
            const float* dd = (const float*)&d4;
            const float* ii = (const float*)&i4;
#pragma unroll
            for (int j = 0; j < 4; ++j)
                if (rintf(ii[j]) == pid && dd[j] > 3.0f) nib |= 1u << j;
        }
        uint32_t cnt_t = (uint32_t)__popc(nib);
        uint32_t incl = wave_incl_scan(cnt_t, lane);
        uint32_t wtot = __shfl(incl, 63, 64);
        uint32_t pos = segbase + run + incl - cnt_t;
        run += wtot;
        if (nib) {
            const float* dd = (const float*)&d4;
#pragma unroll
            for (int j = 0; j < 4; ++j)
                if ((nib >> j) & 1u) {
                    uint32_t key = __float_as_uint(dd[j]);
                    atomicAdd(&hist[key_bin(key)], 1u);
                    if (pos < seglim) list[pos] = make_uint2(key, (uint32_t)(f * 4 + j));
                    ++pos;
                }
        }
    }
    if (lane == 0) s_wcnt[wv] = run;
    __syncthreads();

    uint32_t n = 0;
    bool over = false;
#pragma unroll
    for (int w = 0; w < NWAVES; ++w) {
        uint32_t c = s_wcnt[w];
        n += c;
        over |= (c > CAPW);
    }

    float* outB = out + (size_t)b * 3 * STRIDE_C + p * (KMAX + 1);

    if (n == 0) {   // uniform: empty -> all zeros incl. flag
        for (int r = tid; r <= KMAX; r += THREADS) {
            outB[r] = 0.f; outB[STRIDE_C + r] = 0.f; outB[2 * STRIDE_C + r] = 0.f;
        }
        return;
    }

    // rank targets (deterministic; computed by every thread)
    uint32_t rank[4]; float posf[2];
    {
        float nf = (float)n;
        posf[0] = 0.25f * fmaxf(nf - 1.0f, 0.0f);
        posf[1] = 0.75f * fmaxf(nf - 1.0f, 0.0f);
        rank[0] = (uint32_t)floorf(posf[0]); rank[1] = (uint32_t)ceilf(posf[0]);
        rank[2] = (uint32_t)floorf(posf[1]); rank[3] = (uint32_t)ceilf(posf[1]);
    }

    if (over) {
        // ---- correctness-only fallback: block-parallel bit descent on global ----
        uint32_t v[4];
        for (int k = 0; k < 4; ++k) {
            if (tid == 0) { s_dprefix = 0; s_dr = rank[k]; }
            __syncthreads();
            for (int bit = 30; bit >= 0; --bit) {
                uint32_t pfx = s_dprefix;
                uint32_t c = 0;
                for (int kk = 0; kk < 15; ++kk) {
                    int f = kk * THREADS + tid;
                    if (f < NF4) {
                        float4 d4 = depth4[f]; float4 i4 = ind4[f];
                        const float* dd = (const float*)&d4;
                        const float* ii = (const float*)&i4;
#pragma unroll
                        for (int j = 0; j < 4; ++j)
                            if (rintf(ii[j]) == pid && dd[j] > 3.0f) {
                                uint32_t key = __float_as_uint(dd[j]);
                                if ((key >> (bit + 1)) == pfx && !((key >> bit) & 1u)) ++c;
                            }
                    }
                }
                c = wave_red_add(c);
                if (lane == 0) s_ws[wv] = c;
                __syncthreads();
                uint32_t c0 = 0;
                for (int w = 0; w < NWAVES; ++w) c0 += s_ws[w];
                if (tid == 0) {
                    if (s_dr < c0) s_dprefix = pfx << 1;
                    else { s_dprefix = (pfx << 1) | 1u; s_dr -= c0; }
                }
                __syncthreads();
            }
            v[k] = s_dprefix;
            __syncthreads();
        }
        float f1 = posf[0] - floorf(posf[0]);
        float f3 = posf[1] - floorf(posf[1]);
        float q1 = __uint_as_float(v[0]) + (__uint_as_float(v[1]) - __uint_as_float(v[0])) * f1;
        float q3 = __uint_as_float(v[2]) + (__uint_as_float(v[3]) - __uint_as_float(v[2])) * f3;
        float iqr = q3 - q1;
        float lb = q1 - 1.5f * iqr, ub = q3 + 1.5f * iqr;
        if (tid == 0) {
            const float* depth = (const float*)depth4;
            const float* ind = (const float*)ind4;
            uint32_t r = 0;
            for (int i = 0; i < NPIX; ++i) {
                float d = depth[i];
                if (rintf(ind[i]) == pid && d > 3.0f && d >= lb && d <= ub) {
                    if (r < KMAX) {
                        int row = i / WID, col = i - row * WID;
                        outB[r] = xc_tab[col] * d;
                        outB[STRIDE_C + r] = yc_tab[row] * d;
                        outB[2 * STRIDE_C + r] = d;
                    }
                    ++r;
                }
            }
            s_dr = r;
        }
        __syncthreads();
        uint32_t count = s_dr;
        uint32_t start = count < KMAX ? count : KMAX;
        for (uint32_t r = start + tid; r < KMAX; r += THREADS) {
            outB[r] = 0.f; outB[STRIDE_C + r] = 0.f; outB[2 * STRIDE_C + r] = 0.f;
        }
        if (tid == 0) {
            outB[KMAX] = (count > 0) ? 1.0f : 0.0f;
            outB[STRIDE_C + KMAX] = 0.f; outB[2 * STRIDE_C + KMAX] = 0.f;
        }
        return;
    }

    const uint32_t wn = s_wcnt[wv];          // my wave's segment length

    // ---- locate rank bins in the fixed-base histogram ----
    if (tid == 0) {
#pragma unroll
        for (int k = 0; k < 4; ++k) s_rank[k] = rank[k];
    }
    __syncthreads();
    locate_ranks(hist, NBIN / THREADS, s_rank, s_tbin, s_tbel, s_ws);

    if (tid == 0) {
        uint32_t uq[4]; int nu = 0;
#pragma unroll
        for (int k = 0; k < 4; ++k) {
            s_res[k] = rank[k] - s_tbel[k];
            int fnd = -1;
            for (int u = 0; u < nu; ++u) if (uq[u] == s_tbin[k]) fnd = u;
            if (fnd < 0) { uq[nu] = s_tbin[k]; fnd = nu; ++nu; }
            s_slot[k] = fnd;
        }
#pragma unroll
        for (int u = 0; u < 4; ++u) { s_u[u] = 0xFFFFFFFFu; gcnt[u] = 0; }
        for (int u = 0; u < nu; ++u) if (hist[uq[u]] <= GCAP) s_u[u] = uq[u];
#pragma unroll
        for (int k = 0; k < 4; ++k) s_desc[k] = (hist[uq[s_slot[k]]] > GCAP) ? 1 : 0;
    }
    __syncthreads();

    // ---- gather candidates for the <=4 unique target bins (wave-local) ----
    for (uint32_t i = segbase + lane; i < segbase + wn; i += 64) {
        uint32_t key = list[i].x;
        uint32_t bin = key_bin(key);
#pragma unroll
        for (int u = 0; u < 4; ++u)
            if (bin == s_u[u]) {
                uint32_t slot = atomicAdd(&gcnt[u], 1u);
                if (slot < GCAP) gbuf[u * GCAP + slot] = key;
            }
    }
    __syncthreads();
    // select: wave k resolves rank k by counting within its gathered bin
    if (wv < 4 && !s_desc[wv]) {
        int u = s_slot[wv];
        uint32_t c = gcnt[u];
        uint32_t res = s_res[wv];
        for (uint32_t i = lane; i < c; i += 64) {
            uint32_t xk = gbuf[u * GCAP + i];
            uint32_t less = 0, eq = 0;
            for (uint32_t j = 0; j < c; ++j) {
                uint32_t y = gbuf[u * GCAP + j];
                less += (y < xk); eq += (y == xk);
            }
            if (res >= less && res < less + eq) s_val[wv] = xk;
        }
    }
    __syncthreads();
    // rare exact fallback: bitwise radix descent over the (segmented) LDS list
    for (int k = 0; k < 4; ++k) if (s_desc[k]) {
        if (tid == 0) { s_dprefix = 0; s_dr = rank[k]; }
        __syncthreads();
        for (int bit = 30; bit >= 0; --bit) {
            uint32_t pfx = s_dprefix;
            uint32_t c = 0;
            for (uint32_t i = segbase + lane; i < segbase + wn; i += 64) {
                uint32_t key = list[i].x;
                if ((key >> (bit + 1)) == pfx && !((key >> bit) & 1u)) ++c;
            }
            c = wave_red_add(c);
            if (lane == 0) s_ws[wv] = c;
            __syncthreads();
            uint32_t c0 = 0;
            for (int w = 0; w < NWAVES; ++w) c0 += s_ws[w];
            if (tid == 0) {
                if (s_dr < c0) s_dprefix = pfx << 1;
                else { s_dprefix = (pfx << 1) | 1u; s_dr -= c0; }
            }
            __syncthreads();
        }
        if (tid == 0) s_val[k] = s_dprefix;
        __syncthreads();
    }

    // lb/ub computed redundantly by every thread (saves a tid0 pass + barrier)
    float lb, ub;
    {
        float f1 = posf[0] - floorf(posf[0]);
        float f3 = posf[1] - floorf(posf[1]);
        float v0 = __uint_as_float(s_val[0]), v1 = __uint_as_float(s_val[1]);
        float v2 = __uint_as_float(s_val[2]), v3 = __uint_as_float(s_val[3]);
        float q1 = v0 + (v1 - v0) * f1;
        float q3 = v2 + (v3 - v2) * f3;
        float iqr = q3 - q1;
        lb = q1 - 1.5f * iqr;
        ub = q3 + 1.5f * iqr;
    }

    // ---- kept-bitmask -> raster ranks (wave-local list walk) ----
    for (uint32_t i = segbase + lane; i < segbase + wn; i += 64) {
        uint2 e = list[i];
        float d = __uint_as_float(e.x);
        if (d >= lb && d <= ub) atomicOr(&vb2[e.y >> 5], 1u << (e.y & 31));
    }
    __syncthreads();
    // per-word prefix via one conflict-free uint4 read per thread
    {
        uint4 v4 = make_uint4(0, 0, 0, 0);
        if (tid < NWPAD / 4) v4 = ((const uint4*)vb2)[tid];
        uint32_t pc0 = (uint32_t)__popc(v4.x), pc1 = (uint32_t)__popc(v4.y);
        uint32_t pc2 = (uint32_t)__popc(v4.z), pc3 = (uint32_t)__popc(v4.w);
        uint32_t lsum = pc0 + pc1 + pc2 + pc3;
        uint32_t inc = wave_incl_scan(lsum, lane);
        if (lane == 63) s_ws[wv] = inc;
        __syncthreads();
        uint32_t rn = inc - lsum;
        for (int w = 0; w < wv; ++w) rn += s_ws[w];
        if (tid < NWPAD / 4) {
            ushort4 w4;
            w4.x = (unsigned short)rn;            rn += pc0;
            w4.y = (unsigned short)rn;            rn += pc1;
            w4.z = (unsigned short)rn;            rn += pc2;
            w4.w = (unsigned short)rn;
            ((ushort4*)wpfx)[tid] = w4;
        }
    }
    __syncthreads();
    uint32_t total = 0;
    for (int w = 0; w < NWAVES; ++w) total += s_ws[w];

    // ---- output: rank from bitmask prefix (wave-local); zero-fill; flag ----
    for (uint32_t i = segbase + lane; i < segbase + wn; i += 64) {
        uint2 e = list[i];
        float d = __uint_as_float(e.x);
        if (d >= lb && d <= ub) {
            uint32_t s = e.y;
            uint32_t w = s >> 5;
            uint32_t r = (uint32_t)wpfx[w] + (uint32_t)__popc(vb2[w] & ((1u << (s & 31)) - 1u));
            if (r < KMAX) {
                uint32_t row = s / WID;
                uint32_t col = s - row * WID;
                outB[r] = xc_tab[col] * d;
                outB[STRIDE_C + r] = yc_tab[row] * d;
                outB[2 * STRIDE_C + r] = d;
            }
        }
    }
    uint32_t start = total < KMAX ? total : KMAX;
    for (uint32_t r = start + tid; r < KMAX; r += THREADS) {
        outB[r] = 0.f; outB[STRIDE_C + r] = 0.f; outB[2 * STRIDE_C + r] = 0.f;
    }
    if (tid == 0) {
        outB[KMAX] = (total > 0) ? 1.0f : 0.0f;
        outB[STRIDE_C + KMAX] = 0.f;
        outB[2 * STRIDE_C + KMAX] = 0.f;
    }
}

extern "C" void kernel_launch(void* const* d_in, const int* in_sizes, int n_in,
                              void* d_out, int out_size, void* d_ws, size_t ws_size,
                              hipStream_t stream) {
    (void)n_in; (void)out_size; (void)d_ws; (void)ws_size;
    const float* in = (const float*)d_in[0];
    float* out = (float*)d_out;
    const int B = in_sizes[0] / (3 * NPIX);
    fused<<<B * PMAX, THREADS, 0, stream>>>(in, out, B);
}

// Round 7
// 98.790 us; speedup vs baseline: 9.1833x; 1.0124x over previous
//
#include <hip/hip_runtime.h>
#include <math.h>

#define HGT 150
#define WID 200
#define NPIX 30000
#define NF4  7500            // NPIX/4
#define KMAX 1024
#define PMAX 5
#define THREADS 512
#define NWAVES 8
#define CAPW 512             // per-wave list capacity; n/wave ~391 +- 20 => 6 sigma
#define CAP  (NWAVES*CAPW)
#define NWORDS 938           // ceil(NPIX/32)
#define NWPAD 940            // padded to uint4 multiple
#define NBIN 1024
#define SHIFT 14             // bin = (key - bits(3.0)) >> 14; depth<16 => <=768 bins used
#define KBASE 0x40400000u    // bits(3.0f); valid keys strictly greater (d > 3.0)
#define GCAP 128
#define STRIDE_C (PMAX*(KMAX+1))

__device__ __forceinline__ uint32_t wave_incl_scan(uint32_t x, int lane) {
#pragma unroll
    for (int off = 1; off < 64; off <<= 1) {
        uint32_t y = __shfl_up(x, (unsigned)off, 64);
        if (lane >= off) x += y;
    }
    return x;
}
__device__ __forceinline__ uint32_t wave_red_add(uint32_t x) {
#pragma unroll
    for (int off = 32; off >= 1; off >>= 1) x += __shfl_xor(x, off, 64);
    return x;
}
__device__ __forceinline__ uint32_t key_bin(uint32_t key) {
    uint32_t d = (key - KBASE) >> SHIFT;     // key > KBASE always (depth > 3.0)
    return d < NBIN ? d : (NBIN - 1);        // clamp stays monotone
}

// Parallel rank-location in a histogram of THREADS*seg bins (validated R2-R6).
// s_tbel[k] = count of elements strictly below bin s_tbin[k].
__device__ void locate_ranks(const uint32_t* hh, int seg, const uint32_t* s_rank,
                             uint32_t* s_tbin, uint32_t* s_tbel, uint32_t* s_ws) {
    const int tid = threadIdx.x, lane = tid & 63, wv = tid >> 6;
    const uint32_t* mine = hh + tid * seg;
    uint32_t segsum = 0;
    for (int j = 0; j < seg; ++j) segsum += mine[j];
    uint32_t inc = wave_incl_scan(segsum, lane);
    if (lane == 63) s_ws[wv] = inc;
    __syncthreads();
    uint32_t tbase = inc - segsum;
    for (int w = 0; w < wv; ++w) tbase += s_ws[w];
#pragma unroll
    for (int k = 0; k < 4; ++k) {
        uint32_t r = s_rank[k];
        if (r >= tbase && r < tbase + segsum) {
            uint32_t c = tbase;
            for (int j = 0; j < seg; ++j) {
                uint32_t h = mine[j];
                if (r < c + h) { s_tbin[k] = (uint32_t)(tid * seg + j); s_tbel[k] = c; break; }
                c += h;
            }
        }
    }
    __syncthreads();
}

__global__ __launch_bounds__(THREADS, 4) void fused(const float* __restrict__ in,
                                                    float* __restrict__ out, int B) {
    // XCD-aware remap: same (blockIdx&7) -> same XCD; contiguous batch range per XCD.
    const int nbp = B * PMAX;
    int x = blockIdx.x, b, p;
    if ((nbp & 7) == 0) {
        int per = nbp >> 3;
        int slot = (x & 7) * per + (x >> 3);
        b = slot / PMAX; p = slot - b * PMAX;
    } else { b = x / PMAX; p = x - b * PMAX; }

    const float pid = (float)(p + 1);
    const float4* __restrict__ depth4 = (const float4*)(in + (size_t)b * 3 * NPIX);
    const float4* __restrict__ ind4   = depth4 + NF4;
    const int tid = threadIdx.x, lane = tid & 63, wv = tid >> 6;

    __shared__ uint32_t keys[CAP];          // 16 KB, 8 wave segments
    __shared__ unsigned short sidx[CAP];    //  8 KB pixel idx per entry
    __shared__ uint32_t hist[NBIN];         //  4 KB
    __shared__ uint32_t vb2[NWPAD];         //  3.76 KB kept-pixel bitmask
    __shared__ unsigned short wpfx[NWPAD];  //  1.88 KB per-word kept prefix
    __shared__ float xc_tab[WID];
    __shared__ float yc_tab[HGT];
    __shared__ uint32_t gbuf[4 * GCAP];     //  2 KB quantile gather
    __shared__ uint32_t gcnt[4];
    __shared__ uint32_t s_ws[NWAVES];
    __shared__ uint32_t s_wcnt[NWAVES];
    __shared__ uint32_t s_rank[4], s_res[4], s_tbin[4], s_tbel[4], s_u[4], s_val[4];
    __shared__ int s_slot[4], s_desc[4];
    __shared__ uint32_t s_dprefix, s_dr;

    // ---- init (vb2 zeroing deferred to the select phase) ----
    for (int i = tid; i < NBIN; i += THREADS) hist[i] = 0;
    {
        const double fxd = (double)WID / (2.0 * tan((81.0 * M_PI / 180.0) * 0.5));
        const double fyd = (double)HGT / (2.0 * tan((59.0 * M_PI / 180.0) * 0.5));
        for (int i = tid; i < WID; i += THREADS) xc_tab[i] = (float)(((double)i - (double)WID / 2.0) / fxd);
        for (int i = tid; i < HGT; i += THREADS) yc_tab[i] = (float)(((double)i - (double)HGT / 2.0) / fyd);
    }
    __syncthreads();

    // ---- Phase A: one global pass; 3 iters buffered per wave scan (5 scans) ----
    const uint32_t segbase = (uint32_t)wv * CAPW;
    const uint32_t seglim = segbase + CAPW;
    uint32_t run = 0;
#pragma unroll
    for (int g = 0; g < 5; ++g) {
        float4 dv[3];
        uint32_t nib[3];
        uint32_t cnt_t = 0;
#pragma unroll
        for (int t = 0; t < 3; ++t) {
            int f = (g * 3 + t) * THREADS + tid;
            nib[t] = 0;
            if (f < NF4) {
                dv[t] = depth4[f];
                float4 i4 = ind4[f];
                const float* dd = (const float*)&dv[t];
                const float* ii = (const float*)&i4;
#pragma unroll
                for (int j = 0; j < 4; ++j)
                    if (rintf(ii[j]) == pid && dd[j] > 3.0f) nib[t] |= 1u << j;
                cnt_t += (uint32_t)__popc(nib[t]);
            }
        }
        uint32_t incl = wave_incl_scan(cnt_t, lane);
        uint32_t wtot = __shfl(incl, 63, 64);
        uint32_t pos = segbase + run + incl - cnt_t;
        run += wtot;
#pragma unroll
        for (int t = 0; t < 3; ++t) {
            if (nib[t]) {
                int f = (g * 3 + t) * THREADS + tid;
                const float* dd = (const float*)&dv[t];
#pragma unroll
                for (int j = 0; j < 4; ++j)
                    if ((nib[t] >> j) & 1u) {
                        uint32_t key = __float_as_uint(dd[j]);
                        atomicAdd(&hist[key_bin(key)], 1u);
                        if (pos < seglim) {
                            keys[pos] = key;
                            sidx[pos] = (unsigned short)(f * 4 + j);
                        }
                        ++pos;
                    }
            }
        }
    }
    if (lane == 0) s_wcnt[wv] = run;
    __syncthreads();

    uint32_t n = 0;
    bool over = false;
#pragma unroll
    for (int w = 0; w < NWAVES; ++w) {
        uint32_t c = s_wcnt[w];
        n += c;
        over |= (c > CAPW);
    }

    float* outB = out + (size_t)b * 3 * STRIDE_C + p * (KMAX + 1);

    if (n == 0) {   // uniform: empty -> all zeros incl. flag
        for (int r = tid; r <= KMAX; r += THREADS) {
            outB[r] = 0.f; outB[STRIDE_C + r] = 0.f; outB[2 * STRIDE_C + r] = 0.f;
        }
        return;
    }

    // rank targets (deterministic; computed by every thread)
    uint32_t rank[4]; float posf[2];
    {
        float nf = (float)n;
        posf[0] = 0.25f * fmaxf(nf - 1.0f, 0.0f);
        posf[1] = 0.75f * fmaxf(nf - 1.0f, 0.0f);
        rank[0] = (uint32_t)floorf(posf[0]); rank[1] = (uint32_t)ceilf(posf[0]);
        rank[2] = (uint32_t)floorf(posf[1]); rank[3] = (uint32_t)ceilf(posf[1]);
    }

    if (over) {
        // ---- correctness-only fallback: block-parallel bit descent on global ----
        uint32_t v[4];
        for (int k = 0; k < 4; ++k) {
            if (tid == 0) { s_dprefix = 0; s_dr = rank[k]; }
            __syncthreads();
            for (int bit = 30; bit >= 0; --bit) {
                uint32_t pfx = s_dprefix;
                uint32_t c = 0;
                for (int kk = 0; kk < 15; ++kk) {
                    int f = kk * THREADS + tid;
                    if (f < NF4) {
                        float4 d4 = depth4[f]; float4 i4 = ind4[f];
                        const float* dd = (const float*)&d4;
                        const float* ii = (const float*)&i4;
#pragma unroll
                        for (int j = 0; j < 4; ++j)
                            if (rintf(ii[j]) == pid && dd[j] > 3.0f) {
                                uint32_t key = __float_as_uint(dd[j]);
                                if ((key >> (bit + 1)) == pfx && !((key >> bit) & 1u)) ++c;
                            }
                    }
                }
                c = wave_red_add(c);
                if (lane == 0) s_ws[wv] = c;
                __syncthreads();
                uint32_t c0 = 0;
                for (int w = 0; w < NWAVES; ++w) c0 += s_ws[w];
                if (tid == 0) {
                    if (s_dr < c0) s_dprefix = pfx << 1;
                    else { s_dprefix = (pfx << 1) | 1u; s_dr -= c0; }
                }
                __syncthreads();
            }
            v[k] = s_dprefix;
            __syncthreads();
        }
        float f1 = posf[0] - floorf(posf[0]);
        float f3 = posf[1] - floorf(posf[1]);
        float q1 = __uint_as_float(v[0]) + (__uint_as_float(v[1]) - __uint_as_float(v[0])) * f1;
        float q3 = __uint_as_float(v[2]) + (__uint_as_float(v[3]) - __uint_as_float(v[2])) * f3;
        float iqr = q3 - q1;
        float lb = q1 - 1.5f * iqr, ub = q3 + 1.5f * iqr;
        if (tid == 0) {
            const float* depth = (const float*)depth4;
            const float* ind = (const float*)ind4;
            uint32_t r = 0;
            for (int i = 0; i < NPIX; ++i) {
                float d = depth[i];
                if (rintf(ind[i]) == pid && d > 3.0f && d >= lb && d <= ub) {
                    if (r < KMAX) {
                        int row = i / WID, col = i - row * WID;
                        outB[r] = xc_tab[col] * d;
                        outB[STRIDE_C + r] = yc_tab[row] * d;
                        outB[2 * STRIDE_C + r] = d;
                    }
                    ++r;
                }
            }
            s_dr = r;
        }
        __syncthreads();
        uint32_t count = s_dr;
        uint32_t start = count < KMAX ? count : KMAX;
        for (uint32_t r = start + tid; r < KMAX; r += THREADS) {
            outB[r] = 0.f; outB[STRIDE_C + r] = 0.f; outB[2 * STRIDE_C + r] = 0.f;
        }
        if (tid == 0) {
            outB[KMAX] = (count > 0) ? 1.0f : 0.0f;
            outB[STRIDE_C + KMAX] = 0.f; outB[2 * STRIDE_C + KMAX] = 0.f;
        }
        return;
    }

    const uint32_t wn = s_wcnt[wv];          // my wave's segment length

    // ---- locate rank bins in the fixed-base histogram ----
    if (tid == 0) {
#pragma unroll
        for (int k = 0; k < 4; ++k) s_rank[k] = rank[k];
    }
    __syncthreads();
    locate_ranks(hist, NBIN / THREADS, s_rank, s_tbin, s_tbel, s_ws);

    if (tid == 0) {
        uint32_t uq[4]; int nu = 0;
#pragma unroll
        for (int k = 0; k < 4; ++k) {
            s_res[k] = rank[k] - s_tbel[k];
            int fnd = -1;
            for (int u = 0; u < nu; ++u) if (uq[u] == s_tbin[k]) fnd = u;
            if (fnd < 0) { uq[nu] = s_tbin[k]; fnd = nu; ++nu; }
            s_slot[k] = fnd;
        }
#pragma unroll
        for (int u = 0; u < 4; ++u) { s_u[u] = 0xFFFFFFFFu; gcnt[u] = 0; }
        for (int u = 0; u < nu; ++u) if (hist[uq[u]] <= GCAP) s_u[u] = uq[u];
#pragma unroll
        for (int k = 0; k < 4; ++k) s_desc[k] = (hist[uq[s_slot[k]]] > GCAP) ? 1 : 0;
    }
    __syncthreads();

    // ---- gather candidates for the <=4 unique target bins (wave-local) ----
    for (uint32_t i = segbase + lane; i < segbase + wn; i += 64) {
        uint32_t key = keys[i];
        uint32_t bin = key_bin(key);
#pragma unroll
        for (int u = 0; u < 4; ++u)
            if (bin == s_u[u]) {
                uint32_t slot = atomicAdd(&gcnt[u], 1u);
                if (slot < GCAP) gbuf[u * GCAP + slot] = key;
            }
    }
    __syncthreads();
    // select on waves 0-3; waves 4-7 zero the kept-bitmask in parallel
    if (wv < 4) {
        if (!s_desc[wv]) {
            int u = s_slot[wv];
            uint32_t c = gcnt[u];
            uint32_t res = s_res[wv];
            for (uint32_t i = lane; i < c; i += 64) {
                uint32_t xk = gbuf[u * GCAP + i];
                uint32_t less = 0, eq = 0;
                for (uint32_t j = 0; j < c; ++j) {
                    uint32_t y = gbuf[u * GCAP + j];
                    less += (y < xk); eq += (y == xk);
                }
                if (res >= less && res < less + eq) s_val[wv] = xk;
            }
        }
    } else {
        for (int i = (wv - 4) * 64 + lane; i < NWPAD; i += 256) vb2[i] = 0;
    }
    __syncthreads();
    // rare exact fallback: bitwise radix descent over the (segmented) LDS list
    for (int k = 0; k < 4; ++k) if (s_desc[k]) {
        if (tid == 0) { s_dprefix = 0; s_dr = rank[k]; }
        __syncthreads();
        for (int bit = 30; bit >= 0; --bit) {
            uint32_t pfx = s_dprefix;
            uint32_t c = 0;
            for (uint32_t i = segbase + lane; i < segbase + wn; i += 64) {
                uint32_t key = keys[i];
                if ((key >> (bit + 1)) == pfx && !((key >> bit) & 1u)) ++c;
            }
            c = wave_red_add(c);
            if (lane == 0) s_ws[wv] = c;
            __syncthreads();
            uint32_t c0 = 0;
            for (int w = 0; w < NWAVES; ++w) c0 += s_ws[w];
            if (tid == 0) {
                if (s_dr < c0) s_dprefix = pfx << 1;
                else { s_dprefix = (pfx << 1) | 1u; s_dr -= c0; }
            }
            __syncthreads();
        }
        if (tid == 0) s_val[k] = s_dprefix;
        __syncthreads();
    }

    // lb/ub computed redundantly by every thread
    float lb, ub;
    {
        float f1 = posf[0] - floorf(posf[0]);
        float f3 = posf[1] - floorf(posf[1]);
        float v0 = __uint_as_float(s_val[0]), v1 = __uint_as_float(s_val[1]);
        float v2 = __uint_as_float(s_val[2]), v3 = __uint_as_float(s_val[3]);
        float q1 = v0 + (v1 - v0) * f1;
        float q3 = v2 + (v3 - v2) * f3;
        float iqr = q3 - q1;
        lb = q1 - 1.5f * iqr;
        ub = q3 + 1.5f * iqr;
    }

    // ---- kept-bitmask -> raster ranks (wave-local list walk) ----
    for (uint32_t i = segbase + lane; i < segbase + wn; i += 64) {
        float d = __uint_as_float(keys[i]);
        if (d >= lb && d <= ub) {
            uint32_t s = sidx[i];
            atomicOr(&vb2[s >> 5], 1u << (s & 31));
        }
    }
    __syncthreads();
    // per-word prefix via one conflict-free uint4 read per thread
    {
        uint4 v4 = make_uint4(0, 0, 0, 0);
        if (tid < NWPAD / 4) v4 = ((const uint4*)vb2)[tid];
        uint32_t pc0 = (uint32_t)__popc(v4.x), pc1 = (uint32_t)__popc(v4.y);
        uint32_t pc2 = (uint32_t)__popc(v4.z), pc3 = (uint32_t)__popc(v4.w);
        uint32_t lsum = pc0 + pc1 + pc2 + pc3;
        uint32_t inc = wave_incl_scan(lsum, lane);
        if (lane == 63) s_ws[wv] = inc;
        __syncthreads();
        uint32_t rn = inc - lsum;
        for (int w = 0; w < wv; ++w) rn += s_ws[w];
        if (tid < NWPAD / 4) {
            ushort4 w4;
            w4.x = (unsigned short)rn;            rn += pc0;
            w4.y = (unsigned short)rn;            rn += pc1;
            w4.z = (unsigned short)rn;            rn += pc2;
            w4.w = (unsigned short)rn;
            ((ushort4*)wpfx)[tid] = w4;
        }
    }
    __syncthreads();
    uint32_t total = 0;
    for (int w = 0; w < NWAVES; ++w) total += s_ws[w];

    // ---- output: rank from bitmask prefix (wave-local); zero-fill; flag ----
    for (uint32_t i = segbase + lane; i < segbase + wn; i += 64) {
        uint32_t key = keys[i];
        float d = __uint_as_float(key);
        if (d >= lb && d <= ub) {
            uint32_t s = sidx[i];
            uint32_t w = s >> 5;
            uint32_t base = wpfx[w];
            if (base < KMAX) {      // skip popc/div for entries past slot K
                uint32_t r = base + (uint32_t)__popc(vb2[w] & ((1u << (s & 31)) - 1u));
                if (r < KMAX) {
                    uint32_t row = s / WID;
                    uint32_t col = s - row * WID;
                    outB[r] = xc_tab[col] * d;
                    outB[STRIDE_C + r] = yc_tab[row] * d;
                    outB[2 * STRIDE_C + r] = d;
                }
            }
        }
    }
    uint32_t start = total < KMAX ? total : KMAX;
    for (uint32_t r = start + tid; r < KMAX; r += THREADS) {
        outB[r] = 0.f; outB[STRIDE_C + r] = 0.f; outB[2 * STRIDE_C + r] = 0.f;
    }
    if (tid == 0) {
        outB[KMAX] = (total > 0) ? 1.0f : 0.0f;
        outB[STRIDE_C + KMAX] = 0.f;
        outB[2 * STRIDE_C + KMAX] = 0.f;
    }
}

extern "C" void kernel_launch(void* const* d_in, const int* in_sizes, int n_in,
                              void* d_out, int out_size, void* d_ws, size_t ws_size,
                              hipStream_t stream) {
    (void)n_in; (void)out_size; (void)d_ws; (void)ws_size;
    const float* in = (const float*)d_in[0];
    float* out = (float*)d_out;
    const int B = in_sizes[0] / (3 * NPIX);
    fused<<<B * PMAX, THREADS, 0, stream>>>(in, out, B);
}